// Round 4
// baseline (1273.969 us; speedup 1.0000x reference)
//
#include <hip/hip_runtime.h>
#include <math.h>

#define BN 16
#define NN 1024
#define DD 384
#define D2 768
#define C2 1536
#define NHEAD 8
#define DH 48

#define SZ_ND   (BN*NN*DD)      /* 6291456  */
#define SZ_N2D  (BN*NN*D2)      /* 12582912 */
#define SZ_NC2  (BN*NN*C2)      /* 25165824 */
#define SZ_QKV  (BN*NN*3*DD)    /* 18874368 */

typedef __bf16 bf16x8 __attribute__((ext_vector_type(8)));
typedef float f32x4v __attribute__((ext_vector_type(4)));
typedef unsigned short u16x4 __attribute__((ext_vector_type(4)));

__device__ __forceinline__ unsigned short f2bf(float x){
  unsigned int u = __float_as_uint(x);
  u += 0x7FFFu + ((u >> 16) & 1u);          // round-nearest-even to bf16
  return (unsigned short)(u >> 16);
}
__device__ __forceinline__ float bf2f(unsigned short h){
  return __uint_as_float(((unsigned int)h) << 16);
}

// ---------------- block reductions (256 threads = 4 waves) ----------------
__device__ __forceinline__ float blockReduceSum256(float v){
  __shared__ float red[4];
  #pragma unroll
  for (int o=32;o;o>>=1) v += __shfl_down(v,o,64);
  if ((threadIdx.x&63)==0) red[threadIdx.x>>6]=v;
  __syncthreads();
  float r = red[0]+red[1]+red[2]+red[3];
  __syncthreads();
  return r;
}
__device__ __forceinline__ float blockReduceMax256(float v){
  __shared__ float red[4];
  #pragma unroll
  for (int o=32;o;o>>=1) v = fmaxf(v, __shfl_down(v,o,64));
  if ((threadIdx.x&63)==0) red[threadIdx.x>>6]=v;
  __syncthreads();
  float r = fmaxf(fmaxf(red[0],red[1]),fmaxf(red[2],red[3]));
  __syncthreads();
  return r;
}

// ---------------- LayerNorm: one block per row (fp32 out) ----------------
__global__ __launch_bounds__(256) void ln_kernel(const float* __restrict__ in,
    const float* __restrict__ g, const float* __restrict__ b,
    float* __restrict__ out, int C){
  const int row = blockIdx.x;
  const float* x = in + (size_t)row*C;
  float s=0.f;
  for (int i=threadIdx.x;i<C;i+=256) s += x[i];
  s = blockReduceSum256(s);
  const float mu = s / (float)C;
  float v=0.f;
  for (int i=threadIdx.x;i<C;i+=256){ float d = x[i]-mu; v += d*d; }
  v = blockReduceSum256(v);
  const float rs = rsqrtf(v/(float)C + 1e-5f);
  float* o = out + (size_t)row*C;
  for (int i=threadIdx.x;i<C;i+=256) o[i] = (x[i]-mu)*rs*g[i] + b[i];
}

// ---------------- LayerNorm with bf16 hi/lo split output ----------------
__global__ __launch_bounds__(256) void ln_split_kernel(const float* __restrict__ in,
    const float* __restrict__ g, const float* __restrict__ b,
    unsigned short* __restrict__ oh, unsigned short* __restrict__ ol, int C){
  const int row = blockIdx.x;
  const float* x = in + (size_t)row*C;
  float s=0.f;
  for (int i=threadIdx.x;i<C;i+=256) s += x[i];
  s = blockReduceSum256(s);
  const float mu = s / (float)C;
  float v=0.f;
  for (int i=threadIdx.x;i<C;i+=256){ float d = x[i]-mu; v += d*d; }
  v = blockReduceSum256(v);
  const float rs = rsqrtf(v/(float)C + 1e-5f);
  unsigned short* ohp = oh + (size_t)row*C;
  unsigned short* olp = ol + (size_t)row*C;
  for (int i=threadIdx.x;i<C;i+=256){
    float val = (x[i]-mu)*rs*g[i] + b[i];
    unsigned short hh = f2bf(val);
    ohp[i] = hh; olp[i] = f2bf(val - bf2f(hh));
  }
}

// ---------------- row softmax (QS: softmax over channels d) ----------------
__global__ __launch_bounds__(256) void rowsoftmax_kernel(const float* __restrict__ in,
    float* __restrict__ out, int C){
  const int row = blockIdx.x;
  const float* x = in + (size_t)row*C;
  float m = -3.0e38f;
  for (int i=threadIdx.x;i<C;i+=256) m = fmaxf(m, x[i]);
  m = blockReduceMax256(m);
  float s = 0.f;
  for (int i=threadIdx.x;i<C;i+=256) s += expf(x[i]-m);
  s = blockReduceSum256(s);
  const float inv = 1.f/s;
  float* o = out + (size_t)row*C;
  for (int i=threadIdx.x;i<C;i+=256) o[i] = expf(x[i]-m)*inv;
}

// ---------------- column softmax over tokens n (KS) ----------------
__global__ __launch_bounds__(256) void colsoftmax_kernel(const float* __restrict__ in,
    float* __restrict__ out){
  const int dl = threadIdx.x & 63;
  const int nc = threadIdx.x >> 6;
  const int d  = blockIdx.x*64 + dl;
  const int b  = blockIdx.y;
  const float* p = in + (size_t)b*NN*DD + d;
  __shared__ float redm[4][64];
  __shared__ float reds[4][64];
  float m = -3.0e38f;
  for (int n=nc*256; n<nc*256+256; n++) m = fmaxf(m, p[(size_t)n*DD]);
  redm[nc][dl] = m; __syncthreads();
  m = fmaxf(fmaxf(redm[0][dl],redm[1][dl]),fmaxf(redm[2][dl],redm[3][dl]));
  float s=0.f;
  for (int n=nc*256;n<nc*256+256;n++) s += expf(p[(size_t)n*DD]-m);
  reds[nc][dl]=s; __syncthreads();
  s = reds[0][dl]+reds[1][dl]+reds[2][dl]+reds[3][dl];
  const float inv = 1.f/s;
  float* q = out + (size_t)b*NN*DD + d;
  for (int n=nc*256;n<nc*256+256;n++) q[(size_t)n*DD] = expf(p[(size_t)n*DD]-m)*inv;
}

// ---------------- channel attention, MFMA version (split bf16 output) ------------
__global__ __launch_bounds__(256) void chattn_mfma_kernel(
    const float* __restrict__ qkv, const float* __restrict__ temp,
    unsigned short* __restrict__ coh, unsigned short* __restrict__ col)
{
  const int bh = blockIdx.x, b = bh >> 3, h = bh & 7;
  const int t = threadIdx.x, w = t >> 6, lane = t & 63;
  const int lr = lane & 15, g = lane >> 4;

  __shared__ __align__(16) unsigned char ldsA[27648];
  unsigned short (*Qh)[72] = (unsigned short(*)[72])(ldsA);
  unsigned short (*Ql)[72] = (unsigned short(*)[72])(ldsA + 6912);
  unsigned short (*Kh)[72] = (unsigned short(*)[72])(ldsA + 13824);
  unsigned short (*Kl)[72] = (unsigned short(*)[72])(ldsA + 20736);
  unsigned short (*Vh)[72] = (unsigned short(*)[72])(ldsA);
  unsigned short (*Vl)[72] = (unsigned short(*)[72])(ldsA + 9216);
  __shared__ unsigned short Ph[48][72], Pl[48][72];
  __shared__ float S[48][49];
  __shared__ float qn[48], kn[48];

  const size_t base = (size_t)b*NN*1152 + (size_t)h*48;

  int agrp[3], apr[3], aoff[3];
  #pragma unroll
  for (int l=0;l<3;l++){
    int idx = l*256+t;
    int mo = (idx>=384) ? 1 : 0;
    int a = idx - mo*384;
    agrp[l] = a%12; apr[l] = a/12; aoff[l] = mo*384;
  }

  f32x4v acc[12];
  #pragma unroll
  for (int i=0;i<12;i++) acc[i] = (f32x4v){0.f,0.f,0.f,0.f};

  float4 cur[3][2];
  #pragma unroll
  for (int l=0;l<3;l++){
    const float* p = qkv + base + (size_t)(apr[l]*2)*1152 + aoff[l] + agrp[l]*4;
    cur[l][0] = *(const float4*)p;
    cur[l][1] = *(const float4*)(p+1152);
  }

  for (int nc=0; nc<16; nc++){
    #pragma unroll
    for (int l=0;l<3;l++){
      unsigned short (*Dh)[72] = aoff[l] ? Kh : Qh;
      unsigned short (*Dl)[72] = aoff[l] ? Kl : Ql;
      const float x0[4] = {cur[l][0].x, cur[l][0].y, cur[l][0].z, cur[l][0].w};
      const float x1[4] = {cur[l][1].x, cur[l][1].y, cur[l][1].z, cur[l][1].w};
      #pragma unroll
      for (int c=0;c<4;c++){
        int d = agrp[l]*4+c;
        unsigned short h0 = f2bf(x0[c]), h1 = f2bf(x1[c]);
        unsigned short l0 = f2bf(x0[c]-bf2f(h0)), l1 = f2bf(x1[c]-bf2f(h1));
        *(unsigned int*)&Dh[d][apr[l]*2] = (unsigned)h0 | ((unsigned)h1<<16);
        *(unsigned int*)&Dl[d][apr[l]*2] = (unsigned)l0 | ((unsigned)l1<<16);
      }
    }
    __syncthreads();
    if (nc < 15){
      #pragma unroll
      for (int l=0;l<3;l++){
        const float* p = qkv + base + (size_t)((nc+1)*64 + apr[l]*2)*1152 + aoff[l] + agrp[l]*4;
        cur[l][0] = *(const float4*)p;
        cur[l][1] = *(const float4*)(p+1152);
      }
    }
    if (w < 3){
      #pragma unroll
      for (int ks=0;ks<2;ks++){
        bf16x8 a_h = *(const bf16x8*)&Qh[w*16+lr][ks*32+g*8];
        bf16x8 a_l = *(const bf16x8*)&Ql[w*16+lr][ks*32+g*8];
        #pragma unroll
        for (int c=0;c<3;c++){
          bf16x8 b_h = *(const bf16x8*)&Kh[c*16+lr][ks*32+g*8];
          bf16x8 b_l = *(const bf16x8*)&Kl[c*16+lr][ks*32+g*8];
          acc[c] = __builtin_amdgcn_mfma_f32_16x16x32_bf16(a_h, b_h, acc[c], 0,0,0);
          acc[c] = __builtin_amdgcn_mfma_f32_16x16x32_bf16(a_l, b_h, acc[c], 0,0,0);
          acc[c] = __builtin_amdgcn_mfma_f32_16x16x32_bf16(a_h, b_l, acc[c], 0,0,0);
        }
      }
    } else {
      #pragma unroll
      for (int ks=0;ks<2;ks++){
        #pragma unroll
        for (int c=0;c<3;c++){
          bf16x8 qh_ = *(const bf16x8*)&Qh[c*16+lr][ks*32+g*8];
          bf16x8 ql_ = *(const bf16x8*)&Ql[c*16+lr][ks*32+g*8];
          bf16x8 kh_ = *(const bf16x8*)&Kh[c*16+lr][ks*32+g*8];
          bf16x8 kl_ = *(const bf16x8*)&Kl[c*16+lr][ks*32+g*8];
          acc[c]   = __builtin_amdgcn_mfma_f32_16x16x32_bf16(qh_, qh_, acc[c],   0,0,0);
          acc[3+c] = __builtin_amdgcn_mfma_f32_16x16x32_bf16(qh_, ql_, acc[3+c], 0,0,0);
          acc[6+c] = __builtin_amdgcn_mfma_f32_16x16x32_bf16(kh_, kh_, acc[6+c], 0,0,0);
          acc[9+c] = __builtin_amdgcn_mfma_f32_16x16x32_bf16(kh_, kl_, acc[9+c], 0,0,0);
        }
      }
    }
    __syncthreads();
  }

  const float tp = temp[h];
  if (w == 3){
    if ((lane>>4) == ((lane&15)>>2)){
      int p = lane & 15, r = p & 3;
      #pragma unroll
      for (int c=0;c<3;c++){
        float q2 = fmaxf(acc[c][r]   + 2.f*acc[3+c][r], 0.f);
        float k2 = fmaxf(acc[6+c][r] + 2.f*acc[9+c][r], 0.f);
        qn[c*16+p] = fmaxf(sqrtf(q2), 1e-12f);
        kn[c*16+p] = fmaxf(sqrtf(k2), 1e-12f);
      }
    }
  }
  __syncthreads();
  if (w < 3){
    #pragma unroll
    for (int c=0;c<3;c++){
      #pragma unroll
      for (int r=0;r<4;r++){
        int i = w*16 + g*4 + r, j = c*16 + lr;
        S[i][j] = acc[c][r]*tp/(qn[i]*kn[j]);
      }
    }
  }
  __syncthreads();

  int vgrp[3], vtk[3];
  #pragma unroll
  for (int l=0;l<3;l++){ int idx=l*256+t; vtk[l]=idx/12; vgrp[l]=idx%12; }
  float4 pv[3];
  #pragma unroll
  for (int l=0;l<3;l++)
    pv[l] = *(const float4*)(qkv + base + (size_t)vtk[l]*1152 + 768 + vgrp[l]*4);

  if (t < 48){
    float m = -3.0e38f;
    for (int j=0;j<48;j++) m = fmaxf(m, S[t][j]);
    float s = 0.f;
    for (int j=0;j<48;j++){ float e_ = expf(S[t][j]-m); S[t][j] = e_; s += e_; }
    float inv = 1.f/s;
    for (int j=0;j<48;j++){
      float p = S[t][j]*inv;
      unsigned short hp = f2bf(p);
      Ph[t][j] = hp; Pl[t][j] = f2bf(p - bf2f(hp));
    }
    #pragma unroll
    for (int j=48;j<64;j++){ Ph[t][j]=0; Pl[t][j]=0; }
  } else {
    const u16x4 z4 = (u16x4){0,0,0,0};
    for (int idx=t-48; idx<512; idx+=208){
      int tk = idx>>3, q = idx&7;
      if (q<4) *(u16x4*)&Vh[tk][48+(q&3)*4] = z4;
      else     *(u16x4*)&Vl[tk][48+(q&3)*4] = z4;
    }
  }
  __syncthreads();

  bf16x8 pfh[3][2], pfl[3][2];
  #pragma unroll
  for (int it=0;it<3;it++)
    #pragma unroll
    for (int ks=0;ks<2;ks++){
      pfh[it][ks] = *(const bf16x8*)&Ph[it*16+lr][ks*32+g*8];
      pfl[it][ks] = *(const bf16x8*)&Pl[it*16+lr][ks*32+g*8];
    }

  for (int vc=0; vc<16; vc++){
    #pragma unroll
    for (int l=0;l<3;l++){
      const float xv[4] = {pv[l].x, pv[l].y, pv[l].z, pv[l].w};
      u16x4 hv, lv;
      #pragma unroll
      for (int c=0;c<4;c++){
        unsigned short hh = f2bf(xv[c]);
        hv[c] = hh; lv[c] = f2bf(xv[c] - bf2f(hh));
      }
      *(u16x4*)&Vh[vtk[l]][vgrp[l]*4] = hv;
      *(u16x4*)&Vl[vtk[l]][vgrp[l]*4] = lv;
    }
    __syncthreads();
    if (vc < 15){
      #pragma unroll
      for (int l=0;l<3;l++)
        pv[l] = *(const float4*)(qkv + base + (size_t)((vc+1)*64+vtk[l])*1152 + 768 + vgrp[l]*4);
    }
    bf16x8 vfh[2], vfl[2];
    #pragma unroll
    for (int ks=0;ks<2;ks++){
      vfh[ks] = *(const bf16x8*)&Vh[w*16+lr][ks*32+g*8];
      vfl[ks] = *(const bf16x8*)&Vl[w*16+lr][ks*32+g*8];
    }
    f32x4v o[3];
    #pragma unroll
    for (int it=0;it<3;it++) o[it] = (f32x4v){0.f,0.f,0.f,0.f};
    #pragma unroll
    for (int it=0;it<3;it++)
      #pragma unroll
      for (int ks=0;ks<2;ks++){
        o[it] = __builtin_amdgcn_mfma_f32_16x16x32_bf16(pfh[it][ks], vfh[ks], o[it], 0,0,0);
        o[it] = __builtin_amdgcn_mfma_f32_16x16x32_bf16(pfl[it][ks], vfh[ks], o[it], 0,0,0);
        o[it] = __builtin_amdgcn_mfma_f32_16x16x32_bf16(pfh[it][ks], vfl[ks], o[it], 0,0,0);
      }
    const int n = vc*64 + w*16 + lr;
    #pragma unroll
    for (int it=0;it<3;it++){
      const size_t off = ((size_t)b*NN + n)*DD + h*48 + it*16 + g*4;
      u16x4 hv, lv;
      #pragma unroll
      for (int r=0;r<4;r++){
        float x = o[it][r];
        unsigned short hh = f2bf(x);
        hv[r] = hh; lv[r] = f2bf(x - bf2f(hh));
      }
      *(u16x4*)(coh + off) = hv;
      *(u16x4*)(col + off) = lv;
    }
    __syncthreads();
  }
}

// ---------------- tiled fp32 GEMM (kept for small batched GEMMs) ----------------
template<bool AT_, bool BT_, bool BIAS_, bool RES_>
__global__ __launch_bounds__(256) void gemm64_kernel(const float* __restrict__ A,
    const float* __restrict__ Bm, const float* __restrict__ bias,
    const float* __restrict__ res, float* __restrict__ Cc,
    int M, int Nd, int K, size_t sA, size_t sB, size_t sC)
{
  A  += (size_t)blockIdx.z*sA;
  Bm += (size_t)blockIdx.z*sB;
  Cc += (size_t)blockIdx.z*sC;
  const float* resp = RES_ ? res + (size_t)blockIdx.z*sC : nullptr;
  const int m0 = blockIdx.y*64, n0 = blockIdx.x*64;
  const int t = threadIdx.x, tx = t&15, ty = t>>4;
  __shared__ float As[16][68];
  __shared__ float Bs[16][68];
  float acc[4][4];
  #pragma unroll
  for (int i=0;i<4;i++)
    #pragma unroll
    for (int j=0;j<4;j++) acc[i][j]=0.f;

  for (int k0=0;k0<K;k0+=16){
    if (!AT_){
      const int r = t>>2, c4 = t&3;
      float4 av = *(const float4*)(A + (size_t)(m0+r)*K + k0 + c4*4);
      As[c4*4+0][r]=av.x; As[c4*4+1][r]=av.y; As[c4*4+2][r]=av.z; As[c4*4+3][r]=av.w;
    } else {
      const int r = t>>4, c4 = t&15;
      float4 av = *(const float4*)(A + (size_t)(k0+r)*M + m0 + c4*4);
      *(float4*)&As[r][c4*4] = av;
    }
    if (!BT_){
      const int r = t>>4, c4 = t&15;
      float4 bv = *(const float4*)(Bm + (size_t)(k0+r)*Nd + n0 + c4*4);
      *(float4*)&Bs[r][c4*4] = bv;
    } else {
      const int r = t>>2, c4 = t&3;
      float4 bv = *(const float4*)(Bm + (size_t)(n0+r)*K + k0 + c4*4);
      Bs[c4*4+0][r]=bv.x; Bs[c4*4+1][r]=bv.y; Bs[c4*4+2][r]=bv.z; Bs[c4*4+3][r]=bv.w;
    }
    __syncthreads();
    #pragma unroll
    for (int k=0;k<16;k++){
      const float4 a4 = *(const float4*)&As[k][ty*4];
      const float4 b4 = *(const float4*)&Bs[k][tx*4];
      float a_[4] = {a4.x,a4.y,a4.z,a4.w};
      float b_[4] = {b4.x,b4.y,b4.z,b4.w};
      #pragma unroll
      for (int i=0;i<4;i++)
        #pragma unroll
        for (int j=0;j<4;j++) acc[i][j] += a_[i]*b_[j];
    }
    __syncthreads();
  }
  float bv_[4];
  if (BIAS_){
    #pragma unroll
    for (int j=0;j<4;j++) bv_[j] = bias[n0 + tx*4 + j];
  }
  #pragma unroll
  for (int i=0;i<4;i++){
    const size_t row = (size_t)(m0 + ty*4 + i);
    float* Crow = Cc + row*Nd + n0 + tx*4;
    const float* Rrow = RES_ ? (resp + row*Nd + n0 + tx*4) : nullptr;
    #pragma unroll
    for (int j=0;j<4;j++){
      float v = acc[i][j];
      if (BIAS_) v += bv_[j];
      if (RES_)  v += Rrow[j];
      Crow[j] = v;
    }
  }
}

// ---------------- weight prep: transpose [K,N] -> bf16 hi/lo [N][K] ----------------
__global__ __launch_bounds__(256) void wconv_t_kernel(const float* __restrict__ in,
    unsigned short* __restrict__ oh, unsigned short* __restrict__ ol, int K, int N){
  __shared__ float tile[32][33];
  const int n0 = blockIdx.x*32, k0 = blockIdx.y*32;
  const int j = threadIdx.x & 31, i4 = threadIdx.x >> 5;
  #pragma unroll
  for (int s=0;s<4;s++){
    int i = i4*4+s;
    tile[i][j] = in[(size_t)(k0+i)*N + n0 + j];
  }
  __syncthreads();
  #pragma unroll
  for (int s=0;s<4;s++){
    int i = i4*4+s;
    float x = tile[j][i];                       // in[k0+j][n0+i]
    unsigned short h = f2bf(x);
    oh[(size_t)(n0+i)*K + k0 + j] = h;
    ol[(size_t)(n0+i)*K + k0 + j] = f2bf(x - bf2f(h));
  }
}

// ---------------- elementwise split fp32 -> bf16 hi/lo ----------------
__global__ __launch_bounds__(256) void wconv_kernel(const float* __restrict__ in,
    unsigned short* __restrict__ oh, unsigned short* __restrict__ ol, int n){
  int i = blockIdx.x*256 + threadIdx.x;
  if (i < n){
    float x = in[i];
    unsigned short h = f2bf(x);
    oh[i] = h;
    ol[i] = f2bf(x - bf2f(h));
  }
}

// ---------------- bf16x3 MFMA GEMM, pre-split A and B ----------------
// C[M,N] = A (bf16 hi/lo [M][K]) * B (bf16 hi/lo [N][K]) (+bias)(+res)
// 128x128 tile, BK=32, 4 waves. LDS [128][40] with 16B-block XOR swizzle
// (blk ^= (row>>3)&3): staging writes and ds_read_b128 frag reads conflict-free.
// XCD-swizzled block id (all grids %8==0).
template<bool BIAS_, bool RES_>
__global__ __launch_bounds__(256) void gemm_bf16x3s_kernel(
    const unsigned short* __restrict__ Ah, const unsigned short* __restrict__ Al,
    const unsigned short* __restrict__ Bh, const unsigned short* __restrict__ Bl,
    const float* __restrict__ bias, const float* __restrict__ res,
    float* __restrict__ C, int M, int N, int K)
{
  const int t = threadIdx.x;
  const int nwg = gridDim.x*gridDim.y;
  const int lin = blockIdx.y*gridDim.x + blockIdx.x;
  const int swz = (lin & 7)*(nwg >> 3) + (lin >> 3);
  const int bx = swz % gridDim.x, by = swz / gridDim.x;
  const int m0 = by*128, n0 = bx*128;

  __shared__ unsigned short As_h[128][40];
  __shared__ unsigned short As_l[128][40];
  __shared__ unsigned short Bs_h[128][40];
  __shared__ unsigned short Bs_l[128][40];

  const unsigned short* Ahb = Ah + (size_t)m0*K;
  const unsigned short* Alb = Al + (size_t)m0*K;
  const unsigned short* Bhb = Bh + (size_t)n0*K;
  const unsigned short* Blb = Bl + (size_t)n0*K;

  f32x4v acc[4][4];
  #pragma unroll
  for (int i=0;i<4;i++)
    #pragma unroll
    for (int j=0;j<4;j++) acc[i][j] = (f32x4v){0.f,0.f,0.f,0.f};

  const int w  = t >> 6;
  const int wm = w >> 1, wn = w & 1;
  const int lr = t & 15, g = (t & 63) >> 4;
  const int srow = t >> 1, sc0 = (t & 1)*2;
  const int ssw = (srow >> 3) & 3;

  for (int k0 = 0; k0 < K; k0 += 32){
    #pragma unroll
    for (int c=0;c<2;c++){
      const int cc = sc0 + c, cs = cc ^ ssw;
      const size_t go = (size_t)srow*K + k0 + cc*8;
      *(uint4*)&As_h[srow][cs*8] = *(const uint4*)(Ahb + go);
      *(uint4*)&As_l[srow][cs*8] = *(const uint4*)(Alb + go);
      *(uint4*)&Bs_h[srow][cs*8] = *(const uint4*)(Bhb + go);
      *(uint4*)&Bs_l[srow][cs*8] = *(const uint4*)(Blb + go);
    }
    __syncthreads();

    bf16x8 ah[4], al[4], bhf[4], blf[4];
    #pragma unroll
    for (int i=0;i<4;i++){
      const int ra = wm*64 + i*16 + lr;
      const int ka = (g ^ ((ra>>3)&3))*8;
      ah[i]  = *(const bf16x8*)&As_h[ra][ka];
      al[i]  = *(const bf16x8*)&As_l[ra][ka];
      const int rb = wn*64 + i*16 + lr;
      const int kb = (g ^ ((rb>>3)&3))*8;
      bhf[i] = *(const bf16x8*)&Bs_h[rb][kb];
      blf[i] = *(const bf16x8*)&Bs_l[rb][kb];
    }
    #pragma unroll
    for (int mi=0;mi<4;mi++)
      #pragma unroll
      for (int ni=0;ni<4;ni++){
        f32x4v c_ = acc[mi][ni];
        c_ = __builtin_amdgcn_mfma_f32_16x16x32_bf16(ah[mi], bhf[ni], c_, 0,0,0);
        c_ = __builtin_amdgcn_mfma_f32_16x16x32_bf16(al[mi], bhf[ni], c_, 0,0,0);
        c_ = __builtin_amdgcn_mfma_f32_16x16x32_bf16(ah[mi], blf[ni], c_, 0,0,0);
        acc[mi][ni] = c_;
      }
    __syncthreads();
  }

  #pragma unroll
  for (int ni=0;ni<4;ni++){
    const int col = n0 + wn*64 + ni*16 + lr;
    const float bb = BIAS_ ? bias[col] : 0.f;
    #pragma unroll
    for (int mi=0;mi<4;mi++){
      const int r0 = m0 + wm*64 + mi*16 + g*4;
      #pragma unroll
      for (int r=0;r<4;r++){
        float v = acc[mi][ni][r] + bb;
        if (RES_) v += res[(size_t)(r0+r)*N + col];
        C[(size_t)(r0+r)*N + col] = v;
      }
    }
  }
}

// ---------------- LN(rep) + concat residual -> tx ----------------
__global__ __launch_bounds__(256) void ln_concat_kernel(const float* __restrict__ rep,
    const float* __restrict__ g, const float* __restrict__ b,
    const float* __restrict__ ch1, const float* __restrict__ ch2,
    float* __restrict__ tx){
  const int row = blockIdx.x;
  const float* x = rep + (size_t)row*D2;
  float s=0.f;
  for (int i=threadIdx.x;i<D2;i+=256) s += x[i];
  s = blockReduceSum256(s);
  const float mu = s / (float)D2;
  float v=0.f;
  for (int i=threadIdx.x;i<D2;i+=256){ float d = x[i]-mu; v += d*d; }
  v = blockReduceSum256(v);
  const float rs = rsqrtf(v/(float)D2 + 1e-5f);
  float* o = tx + (size_t)row*D2;
  for (int i=threadIdx.x;i<D2;i+=256){
    float val = (x[i]-mu)*rs*g[i] + b[i];
    float rv = (i<DD) ? ch1[(size_t)row*DD + i] : ch2[(size_t)row*DD + i - DD];
    o[i] = val + rv;
  }
}

// ---------------- depthwise 3x3 conv + bias + exact GELU (split bf16 out) --------
__global__ __launch_bounds__(256) void dwconv_gelu_kernel(const float* __restrict__ h1,
    const float* __restrict__ w, const float* __restrict__ bias,
    unsigned short* __restrict__ gh, unsigned short* __restrict__ gl){
  const int idx = blockIdx.x*256 + threadIdx.x;   // 16*32*384 = 196608 total
  const int b   = idx / 12288;                    // 12288 = 32*384 (uniform per block)
  const int r   = idx - b*12288;
  const int hh  = r / 384;
  const int c4  = r - hh*384;
  const int c   = c4*4;
  const float* base = h1 + (size_t)b*NN*C2 + c;
  const size_t obase = ((size_t)b*NN + hh*32)*C2 + c;

  f32x4v wk[9];
  #pragma unroll
  for (int k=0;k<9;k++){
    f32x4v t_;
    #pragma unroll
    for (int q=0;q<4;q++) t_[q] = w[(size_t)(c+q)*9 + k];
    wk[k] = t_;
  }
  f32x4v bvv;
  {
    const float4 bb = *(const float4*)(bias + c);
    bvv = (f32x4v){bb.x, bb.y, bb.z, bb.w};
  }

  const bool hm = (hh > 0), hp = (hh < 31);
  const f32x4v z4 = (f32x4v){0.f,0.f,0.f,0.f};
  const size_t rm = (size_t)((hh-1)*32)*C2;
  const size_t r0 = (size_t)( hh   *32)*C2;
  const size_t rp = (size_t)((hh+1)*32)*C2;

  f32x4v A0,A1,A2, B0,B1,B2, C0,C1,C2c;
  A0=z4; A1=z4; A2=z4;
  B0 = hm ? *(const f32x4v*)(base + rm) : z4;
  B1 =      *(const f32x4v*)(base + r0);
  B2 = hp ? *(const f32x4v*)(base + rp) : z4;
  C0 = hm ? *(const f32x4v*)(base + rm + C2) : z4;
  C1 =      *(const f32x4v*)(base + r0 + C2);
  C2c= hp ? *(const f32x4v*)(base + rp + C2) : z4;

  for (int ww=0; ww<32; ww++){
    f32x4v N0,N1,N2;
    if (ww < 30){
      const size_t co_ = (size_t)(ww+2)*C2;
      N0 = hm ? *(const f32x4v*)(base + rm + co_) : z4;
      N1 =      *(const f32x4v*)(base + r0 + co_) ;
      N2 = hp ? *(const f32x4v*)(base + rp + co_) : z4;
    } else { N0=z4; N1=z4; N2=z4; }

    f32x4v s = bvv;
    s += wk[0]*A0 + wk[1]*B0 + wk[2]*C0;
    s += wk[3]*A1 + wk[4]*B1 + wk[5]*C1;
    s += wk[6]*A2 + wk[7]*B2 + wk[8]*C2c;

    u16x4 hv, lv;
    #pragma unroll
    for (int q=0;q<4;q++){
      float rlt = 0.5f*s[q]*(1.f + erff(s[q]*0.70710678118654752f));
      unsigned short hhv = f2bf(rlt);
      hv[q] = hhv; lv[q] = f2bf(rlt - bf2f(hhv));
    }
    *(u16x4*)(gh + obase + (size_t)ww*C2) = hv;
    *(u16x4*)(gl + obase + (size_t)ww*C2) = lv;

    A0=B0; A1=B1; A2=B2;
    B0=C0; B1=C1; B2=C2c;
    C0=N0; C1=N1; C2c=N2;
  }
}

// ---------------- launch ----------------
extern "C" void kernel_launch(void* const* d_in, const int* in_sizes, int n_in,
                              void* d_out, int out_size, void* d_ws, size_t ws_size,
                              hipStream_t stream) {
  const float* x1     = (const float*)d_in[0];
  const float* x2     = (const float*)d_in[1];
  const float* ln1_g  = (const float*)d_in[2];
  const float* ln1_b  = (const float*)d_in[3];
  const float* qkv_w  = (const float*)d_in[4];
  const float* ca_temp= (const float*)d_in[5];
  const float* proj_w = (const float*)d_in[6];
  const float* proj_b = (const float*)d_in[7];
  const float* ln3_g  = (const float*)d_in[8];
  const float* ln3_b  = (const float*)d_in[9];
  const float* rp_w   = (const float*)d_in[10];
  const float* rp_b   = (const float*)d_in[11];
  const float* cn_g   = (const float*)d_in[12];
  const float* cn_b   = (const float*)d_in[13];
  const float* ln2_g  = (const float*)d_in[14];
  const float* ln2_b  = (const float*)d_in[15];
  const float* fc1_w  = (const float*)d_in[16];
  const float* fc1_b  = (const float*)d_in[17];
  const float* dw_w   = (const float*)d_in[18];
  const float* dw_b   = (const float*)d_in[19];
  const float* fc2_w  = (const float*)d_in[20];
  const float* fc2_b  = (const float*)d_in[21];
  float* out = (float*)d_out;
  float* W   = (float*)d_ws;

  // ---- workspace layout (peak 50,331,648 floats = 192 MiB) ----
  // Phase A: [0,SZ_ND) = split LN/co planes; qkvb [SZ_ND,25.17M); ch1/ch2; weights @37.75M
  unsigned short* ycoh = (unsigned short*)W;        // SZ_ND u16
  unsigned short* ycol = ycoh + (size_t)SZ_ND;      // SZ_ND u16 (region = SZ_ND floats)
  unsigned short* coh  = ycoh;                      // reuse after qkv GEMM
  unsigned short* col  = ycol;
  float* qkvb = W + (size_t)SZ_ND;
  float* ch1  = W + 25165824ull;
  float* ch2  = W + 31457280ull;
  unsigned short* qkvwT_h  = (unsigned short*)(W + 37748736ull);
  unsigned short* qkvwT_l  = qkvwT_h + 442368u;
  unsigned short* projwT_h = qkvwT_l + 442368u;
  unsigned short* projwT_l = projwT_h + 147456u;
  // Phase B aliases:
  float* n1  = W;
  float* n2  = W + (size_t)SZ_ND;
  float* KS  = W + 2ull*SZ_ND;
  float* QS  = W + 3ull*SZ_ND;
  float* ctx = W + (size_t)SZ_ND;                    // over dead n2
  float* ATb = W;                                    // over dead n1
  unsigned short* ATbh = (unsigned short*)(W + 3ull*SZ_ND);  // over dead QS
  unsigned short* ATbl = ATbh + (size_t)SZ_ND;
  float* rep = W + (size_t)SZ_ND;                    // over dead ctx/KS
  unsigned short* rpw_h = (unsigned short*)(W + 37748736ull);
  unsigned short* rpw_l = rpw_h + 294912u;
  // Phase C aliases:
  float* txp  = out;
  float* h1   = W;                                   // [0,25.17M)
  unsigned short* y2h = (unsigned short*)(W + 25165824ull);  // SZ_N2D u16
  unsigned short* y2l = y2h + (size_t)SZ_N2D;                // ends at 37.75M floats
  unsigned short* fc1wT_h = (unsigned short*)(W + 37748736ull);
  unsigned short* fc1wT_l = fc1wT_h + 1179648u;
  unsigned short* gh = (unsigned short*)(W + 25165824ull);   // over dead y2 (SZ_NC2 u16)
  unsigned short* gl = gh + (size_t)SZ_NC2;                  // [37.75M,50.33M) over dead fc1wT
  unsigned short* fc2wT_h = (unsigned short*)W;              // over dead h1
  unsigned short* fc2wT_l = fc2wT_h + 1179648u;

  const int M = BN*NN;

  // ---- phase-A weight prep ----
  wconv_t_kernel<<<dim3(1152/32, DD/32), dim3(256), 0, stream>>>(qkv_w, qkvwT_h, qkvwT_l, DD, 1152);
  wconv_t_kernel<<<dim3(DD/32, DD/32), dim3(256), 0, stream>>>(proj_w, projwT_h, projwT_l, DD, DD);

  // ---- channel attention, stream 1 ----
  ln_split_kernel<<<dim3(M), dim3(256), 0, stream>>>(x1, ln1_g, ln1_b, ycoh, ycol, DD);
  gemm_bf16x3s_kernel<false,false><<<dim3(1152/128, M/128), dim3(256), 0, stream>>>(
      ycoh, ycol, qkvwT_h, qkvwT_l, nullptr, nullptr, qkvb, M, 1152, DD);
  chattn_mfma_kernel<<<dim3(BN*NHEAD), dim3(256), 0, stream>>>(qkvb, ca_temp, coh, col);
  gemm_bf16x3s_kernel<true,true><<<dim3(DD/128, M/128), dim3(256), 0, stream>>>(
      coh, col, projwT_h, projwT_l, proj_b, x1, ch1, M, DD, DD);

  // ---- channel attention, stream 2 ----
  ln_split_kernel<<<dim3(M), dim3(256), 0, stream>>>(x2, ln1_g, ln1_b, ycoh, ycol, DD);
  gemm_bf16x3s_kernel<false,false><<<dim3(1152/128, M/128), dim3(256), 0, stream>>>(
      ycoh, ycol, qkvwT_h, qkvwT_l, nullptr, nullptr, qkvb, M, 1152, DD);
  chattn_mfma_kernel<<<dim3(BN*NHEAD), dim3(256), 0, stream>>>(qkvb, ca_temp, coh, col);
  gemm_bf16x3s_kernel<true,true><<<dim3(DD/128, M/128), dim3(256), 0, stream>>>(
      coh, col, projwT_h, projwT_l, proj_b, x2, ch2, M, DD, DD);

  // ---- cross attention ----
  wconv_kernel<<<dim3(294912/256), dim3(256), 0, stream>>>(rp_w, rpw_h, rpw_l, 294912);
  ln_kernel<<<dim3(M), dim3(256), 0, stream>>>(ch1, ln3_g, ln3_b, n1, DD);
  ln_kernel<<<dim3(M), dim3(256), 0, stream>>>(ch2, ln3_g, ln3_b, n2, DD);
  rowsoftmax_kernel<<<dim3(M), dim3(256), 0, stream>>>(n2, QS, DD);
  colsoftmax_kernel<<<dim3(DD/64, BN), dim3(256), 0, stream>>>(n2, KS);
  gemm64_kernel<true,false,false,false><<<dim3(DD/64, DD/64, BN), dim3(256), 0, stream>>>(
      KS, n1, nullptr, nullptr, ctx, DD, DD, NN,
      (size_t)NN*DD, (size_t)NN*DD, (size_t)DD*DD);
  gemm64_kernel<false,false,false,false><<<dim3(DD/64, NN/64, BN), dim3(256), 0, stream>>>(
      QS, ctx, nullptr, nullptr, ATb, NN, DD, DD,
      (size_t)NN*DD, (size_t)DD*DD, (size_t)NN*DD);
  wconv_kernel<<<dim3(SZ_ND/256), dim3(256), 0, stream>>>(ATb, ATbh, ATbl, SZ_ND);
  gemm_bf16x3s_kernel<true,false><<<dim3(D2/128, M/128), dim3(256), 0, stream>>>(
      ATbh, ATbl, rpw_h, rpw_l, rp_b, nullptr, rep, M, D2, DD);
  ln_concat_kernel<<<dim3(M), dim3(256), 0, stream>>>(rep, cn_g, cn_b, ch1, ch2, txp);

  // ---- mix FFN ----
  wconv_t_kernel<<<dim3(C2/32, D2/32), dim3(256), 0, stream>>>(fc1_w, fc1wT_h, fc1wT_l, D2, C2);
  ln_split_kernel<<<dim3(M), dim3(256), 0, stream>>>(txp, ln2_g, ln2_b, y2h, y2l, D2);
  gemm_bf16x3s_kernel<true,false><<<dim3(C2/128, M/128), dim3(256), 0, stream>>>(
      y2h, y2l, fc1wT_h, fc1wT_l, fc1_b, nullptr, h1, M, C2, D2);
  dwconv_gelu_kernel<<<dim3(196608/256), dim3(256), 0, stream>>>(h1, dw_w, dw_b, gh, gl);
  wconv_t_kernel<<<dim3(D2/32, C2/32), dim3(256), 0, stream>>>(fc2_w, fc2wT_h, fc2wT_l, C2, D2);
  gemm_bf16x3s_kernel<true,true><<<dim3(D2/128, M/128), dim3(256), 0, stream>>>(
      gh, gl, fc2wT_h, fc2wT_l, fc2_b, txp, out, M, D2, C2);
}

// Round 5
// 1117.735 us; speedup vs baseline: 1.1398x; 1.1398x over previous
//
#include <hip/hip_runtime.h>
#include <math.h>

#define BN 16
#define NN 1024
#define DD 384
#define D2 768
#define C2 1536
#define NHEAD 8
#define DH 48

#define SZ_ND   (BN*NN*DD)      /* 6291456  */
#define SZ_N2D  (BN*NN*D2)      /* 12582912 */
#define SZ_NC2  (BN*NN*C2)      /* 25165824 */
#define SZ_QKV  (BN*NN*3*DD)    /* 18874368 */

typedef __bf16 bf16x8 __attribute__((ext_vector_type(8)));
typedef float f32x4v __attribute__((ext_vector_type(4)));
typedef unsigned short u16x4 __attribute__((ext_vector_type(4)));

__device__ __forceinline__ unsigned short f2bf(float x){
  unsigned int u = __float_as_uint(x);
  u += 0x7FFFu + ((u >> 16) & 1u);          // round-nearest-even to bf16
  return (unsigned short)(u >> 16);
}
__device__ __forceinline__ float bf2f(unsigned short h){
  return __uint_as_float(((unsigned int)h) << 16);
}

// ---------------- block reductions (256 threads = 4 waves) ----------------
__device__ __forceinline__ float blockReduceSum256(float v){
  __shared__ float red[4];
  #pragma unroll
  for (int o=32;o;o>>=1) v += __shfl_down(v,o,64);
  if ((threadIdx.x&63)==0) red[threadIdx.x>>6]=v;
  __syncthreads();
  float r = red[0]+red[1]+red[2]+red[3];
  __syncthreads();
  return r;
}
__device__ __forceinline__ float blockReduceMax256(float v){
  __shared__ float red[4];
  #pragma unroll
  for (int o=32;o;o>>=1) v = fmaxf(v, __shfl_down(v,o,64));
  if ((threadIdx.x&63)==0) red[threadIdx.x>>6]=v;
  __syncthreads();
  float r = fmaxf(fmaxf(red[0],red[1]),fmaxf(red[2],red[3]));
  __syncthreads();
  return r;
}

// ---------------- LayerNorm: one block per row (fp32 out) ----------------
__global__ __launch_bounds__(256) void ln_kernel(const float* __restrict__ in,
    const float* __restrict__ g, const float* __restrict__ b,
    float* __restrict__ out, int C){
  const int row = blockIdx.x;
  const float* x = in + (size_t)row*C;
  float s=0.f;
  for (int i=threadIdx.x;i<C;i+=256) s += x[i];
  s = blockReduceSum256(s);
  const float mu = s / (float)C;
  float v=0.f;
  for (int i=threadIdx.x;i<C;i+=256){ float d = x[i]-mu; v += d*d; }
  v = blockReduceSum256(v);
  const float rs = rsqrtf(v/(float)C + 1e-5f);
  float* o = out + (size_t)row*C;
  for (int i=threadIdx.x;i<C;i+=256) o[i] = (x[i]-mu)*rs*g[i] + b[i];
}

// ---------------- LayerNorm with bf16 hi/lo split output ----------------
__global__ __launch_bounds__(256) void ln_split_kernel(const float* __restrict__ in,
    const float* __restrict__ g, const float* __restrict__ b,
    unsigned short* __restrict__ oh, unsigned short* __restrict__ ol, int C){
  const int row = blockIdx.x;
  const float* x = in + (size_t)row*C;
  float s=0.f;
  for (int i=threadIdx.x;i<C;i+=256) s += x[i];
  s = blockReduceSum256(s);
  const float mu = s / (float)C;
  float v=0.f;
  for (int i=threadIdx.x;i<C;i+=256){ float d = x[i]-mu; v += d*d; }
  v = blockReduceSum256(v);
  const float rs = rsqrtf(v/(float)C + 1e-5f);
  unsigned short* ohp = oh + (size_t)row*C;
  unsigned short* olp = ol + (size_t)row*C;
  for (int i=threadIdx.x;i<C;i+=256){
    float val = (x[i]-mu)*rs*g[i] + b[i];
    unsigned short hh = f2bf(val);
    ohp[i] = hh; olp[i] = f2bf(val - bf2f(hh));
  }
}

// ---------------- row softmax (QS: softmax over channels d) ----------------
__global__ __launch_bounds__(256) void rowsoftmax_kernel(const float* __restrict__ in,
    float* __restrict__ out, int C){
  const int row = blockIdx.x;
  const float* x = in + (size_t)row*C;
  float m = -3.0e38f;
  for (int i=threadIdx.x;i<C;i+=256) m = fmaxf(m, x[i]);
  m = blockReduceMax256(m);
  float s = 0.f;
  for (int i=threadIdx.x;i<C;i+=256) s += expf(x[i]-m);
  s = blockReduceSum256(s);
  const float inv = 1.f/s;
  float* o = out + (size_t)row*C;
  for (int i=threadIdx.x;i<C;i+=256) o[i] = expf(x[i]-m)*inv;
}

// ---------------- column softmax over tokens n (KS) ----------------
__global__ __launch_bounds__(256) void colsoftmax_kernel(const float* __restrict__ in,
    float* __restrict__ out){
  const int dl = threadIdx.x & 63;
  const int nc = threadIdx.x >> 6;
  const int d  = blockIdx.x*64 + dl;
  const int b  = blockIdx.y;
  const float* p = in + (size_t)b*NN*DD + d;
  __shared__ float redm[4][64];
  __shared__ float reds[4][64];
  float m = -3.0e38f;
  for (int n=nc*256; n<nc*256+256; n++) m = fmaxf(m, p[(size_t)n*DD]);
  redm[nc][dl] = m; __syncthreads();
  m = fmaxf(fmaxf(redm[0][dl],redm[1][dl]),fmaxf(redm[2][dl],redm[3][dl]));
  float s=0.f;
  for (int n=nc*256;n<nc*256+256;n++) s += expf(p[(size_t)n*DD]-m);
  reds[nc][dl]=s; __syncthreads();
  s = reds[0][dl]+reds[1][dl]+reds[2][dl]+reds[3][dl];
  const float inv = 1.f/s;
  float* q = out + (size_t)b*NN*DD + d;
  for (int n=nc*256;n<nc*256+256;n++) q[(size_t)n*DD] = expf(p[(size_t)n*DD]-m)*inv;
}

// ---------------- channel attention, MFMA version (split bf16 output) ------------
__global__ __launch_bounds__(256) void chattn_mfma_kernel(
    const float* __restrict__ qkv, const float* __restrict__ temp,
    unsigned short* __restrict__ coh, unsigned short* __restrict__ col)
{
  const int bh = blockIdx.x, b = bh >> 3, h = bh & 7;
  const int t = threadIdx.x, w = t >> 6, lane = t & 63;
  const int lr = lane & 15, g = lane >> 4;

  __shared__ __align__(16) unsigned char ldsA[27648];
  unsigned short (*Qh)[72] = (unsigned short(*)[72])(ldsA);
  unsigned short (*Ql)[72] = (unsigned short(*)[72])(ldsA + 6912);
  unsigned short (*Kh)[72] = (unsigned short(*)[72])(ldsA + 13824);
  unsigned short (*Kl)[72] = (unsigned short(*)[72])(ldsA + 20736);
  unsigned short (*Vh)[72] = (unsigned short(*)[72])(ldsA);
  unsigned short (*Vl)[72] = (unsigned short(*)[72])(ldsA + 9216);
  __shared__ unsigned short Ph[48][72], Pl[48][72];
  __shared__ float S[48][49];
  __shared__ float qn[48], kn[48];

  const size_t base = (size_t)b*NN*1152 + (size_t)h*48;

  int agrp[3], apr[3], aoff[3];
  #pragma unroll
  for (int l=0;l<3;l++){
    int idx = l*256+t;
    int mo = (idx>=384) ? 1 : 0;
    int a = idx - mo*384;
    agrp[l] = a%12; apr[l] = a/12; aoff[l] = mo*384;
  }

  f32x4v acc[12];
  #pragma unroll
  for (int i=0;i<12;i++) acc[i] = (f32x4v){0.f,0.f,0.f,0.f};

  float4 cur[3][2];
  #pragma unroll
  for (int l=0;l<3;l++){
    const float* p = qkv + base + (size_t)(apr[l]*2)*1152 + aoff[l] + agrp[l]*4;
    cur[l][0] = *(const float4*)p;
    cur[l][1] = *(const float4*)(p+1152);
  }

  for (int nc=0; nc<16; nc++){
    #pragma unroll
    for (int l=0;l<3;l++){
      unsigned short (*Dh)[72] = aoff[l] ? Kh : Qh;
      unsigned short (*Dl)[72] = aoff[l] ? Kl : Ql;
      const float x0[4] = {cur[l][0].x, cur[l][0].y, cur[l][0].z, cur[l][0].w};
      const float x1[4] = {cur[l][1].x, cur[l][1].y, cur[l][1].z, cur[l][1].w};
      #pragma unroll
      for (int c=0;c<4;c++){
        int d = agrp[l]*4+c;
        unsigned short h0 = f2bf(x0[c]), h1 = f2bf(x1[c]);
        unsigned short l0 = f2bf(x0[c]-bf2f(h0)), l1 = f2bf(x1[c]-bf2f(h1));
        *(unsigned int*)&Dh[d][apr[l]*2] = (unsigned)h0 | ((unsigned)h1<<16);
        *(unsigned int*)&Dl[d][apr[l]*2] = (unsigned)l0 | ((unsigned)l1<<16);
      }
    }
    __syncthreads();
    if (nc < 15){
      #pragma unroll
      for (int l=0;l<3;l++){
        const float* p = qkv + base + (size_t)((nc+1)*64 + apr[l]*2)*1152 + aoff[l] + agrp[l]*4;
        cur[l][0] = *(const float4*)p;
        cur[l][1] = *(const float4*)(p+1152);
      }
    }
    if (w < 3){
      #pragma unroll
      for (int ks=0;ks<2;ks++){
        bf16x8 a_h = *(const bf16x8*)&Qh[w*16+lr][ks*32+g*8];
        bf16x8 a_l = *(const bf16x8*)&Ql[w*16+lr][ks*32+g*8];
        #pragma unroll
        for (int c=0;c<3;c++){
          bf16x8 b_h = *(const bf16x8*)&Kh[c*16+lr][ks*32+g*8];
          bf16x8 b_l = *(const bf16x8*)&Kl[c*16+lr][ks*32+g*8];
          acc[c] = __builtin_amdgcn_mfma_f32_16x16x32_bf16(a_h, b_h, acc[c], 0,0,0);
          acc[c] = __builtin_amdgcn_mfma_f32_16x16x32_bf16(a_l, b_h, acc[c], 0,0,0);
          acc[c] = __builtin_amdgcn_mfma_f32_16x16x32_bf16(a_h, b_l, acc[c], 0,0,0);
        }
      }
    } else {
      #pragma unroll
      for (int ks=0;ks<2;ks++){
        #pragma unroll
        for (int c=0;c<3;c++){
          bf16x8 qh_ = *(const bf16x8*)&Qh[c*16+lr][ks*32+g*8];
          bf16x8 ql_ = *(const bf16x8*)&Ql[c*16+lr][ks*32+g*8];
          bf16x8 kh_ = *(const bf16x8*)&Kh[c*16+lr][ks*32+g*8];
          bf16x8 kl_ = *(const bf16x8*)&Kl[c*16+lr][ks*32+g*8];
          acc[c]   = __builtin_amdgcn_mfma_f32_16x16x32_bf16(qh_, qh_, acc[c],   0,0,0);
          acc[3+c] = __builtin_amdgcn_mfma_f32_16x16x32_bf16(qh_, ql_, acc[3+c], 0,0,0);
          acc[6+c] = __builtin_amdgcn_mfma_f32_16x16x32_bf16(kh_, kh_, acc[6+c], 0,0,0);
          acc[9+c] = __builtin_amdgcn_mfma_f32_16x16x32_bf16(kh_, kl_, acc[9+c], 0,0,0);
        }
      }
    }
    __syncthreads();
  }

  const float tp = temp[h];
  if (w == 3){
    if ((lane>>4) == ((lane&15)>>2)){
      int p = lane & 15, r = p & 3;
      #pragma unroll
      for (int c=0;c<3;c++){
        float q2 = fmaxf(acc[c][r]   + 2.f*acc[3+c][r], 0.f);
        float k2 = fmaxf(acc[6+c][r] + 2.f*acc[9+c][r], 0.f);
        qn[c*16+p] = fmaxf(sqrtf(q2), 1e-12f);
        kn[c*16+p] = fmaxf(sqrtf(k2), 1e-12f);
      }
    }
  }
  __syncthreads();
  if (w < 3){
    #pragma unroll
    for (int c=0;c<3;c++){
      #pragma unroll
      for (int r=0;r<4;r++){
        int i = w*16 + g*4 + r, j = c*16 + lr;
        S[i][j] = acc[c][r]*tp/(qn[i]*kn[j]);
      }
    }
  }
  __syncthreads();

  int vgrp[3], vtk[3];
  #pragma unroll
  for (int l=0;l<3;l++){ int idx=l*256+t; vtk[l]=idx/12; vgrp[l]=idx%12; }
  float4 pv[3];
  #pragma unroll
  for (int l=0;l<3;l++)
    pv[l] = *(const float4*)(qkv + base + (size_t)vtk[l]*1152 + 768 + vgrp[l]*4);

  if (t < 48){
    float m = -3.0e38f;
    for (int j=0;j<48;j++) m = fmaxf(m, S[t][j]);
    float s = 0.f;
    for (int j=0;j<48;j++){ float e_ = expf(S[t][j]-m); S[t][j] = e_; s += e_; }
    float inv = 1.f/s;
    for (int j=0;j<48;j++){
      float p = S[t][j]*inv;
      unsigned short hp = f2bf(p);
      Ph[t][j] = hp; Pl[t][j] = f2bf(p - bf2f(hp));
    }
    #pragma unroll
    for (int j=48;j<64;j++){ Ph[t][j]=0; Pl[t][j]=0; }
  } else {
    const u16x4 z4 = (u16x4){0,0,0,0};
    for (int idx=t-48; idx<512; idx+=208){
      int tk = idx>>3, q = idx&7;
      if (q<4) *(u16x4*)&Vh[tk][48+(q&3)*4] = z4;
      else     *(u16x4*)&Vl[tk][48+(q&3)*4] = z4;
    }
  }
  __syncthreads();

  bf16x8 pfh[3][2], pfl[3][2];
  #pragma unroll
  for (int it=0;it<3;it++)
    #pragma unroll
    for (int ks=0;ks<2;ks++){
      pfh[it][ks] = *(const bf16x8*)&Ph[it*16+lr][ks*32+g*8];
      pfl[it][ks] = *(const bf16x8*)&Pl[it*16+lr][ks*32+g*8];
    }

  for (int vc=0; vc<16; vc++){
    #pragma unroll
    for (int l=0;l<3;l++){
      const float xv[4] = {pv[l].x, pv[l].y, pv[l].z, pv[l].w};
      u16x4 hv, lv;
      #pragma unroll
      for (int c=0;c<4;c++){
        unsigned short hh = f2bf(xv[c]);
        hv[c] = hh; lv[c] = f2bf(xv[c] - bf2f(hh));
      }
      *(u16x4*)&Vh[vtk[l]][vgrp[l]*4] = hv;
      *(u16x4*)&Vl[vtk[l]][vgrp[l]*4] = lv;
    }
    __syncthreads();
    if (vc < 15){
      #pragma unroll
      for (int l=0;l<3;l++)
        pv[l] = *(const float4*)(qkv + base + (size_t)((vc+1)*64+vtk[l])*1152 + 768 + vgrp[l]*4);
    }
    bf16x8 vfh[2], vfl[2];
    #pragma unroll
    for (int ks=0;ks<2;ks++){
      vfh[ks] = *(const bf16x8*)&Vh[w*16+lr][ks*32+g*8];
      vfl[ks] = *(const bf16x8*)&Vl[w*16+lr][ks*32+g*8];
    }
    f32x4v o[3];
    #pragma unroll
    for (int it=0;it<3;it++) o[it] = (f32x4v){0.f,0.f,0.f,0.f};
    #pragma unroll
    for (int it=0;it<3;it++)
      #pragma unroll
      for (int ks=0;ks<2;ks++){
        o[it] = __builtin_amdgcn_mfma_f32_16x16x32_bf16(pfh[it][ks], vfh[ks], o[it], 0,0,0);
        o[it] = __builtin_amdgcn_mfma_f32_16x16x32_bf16(pfl[it][ks], vfh[ks], o[it], 0,0,0);
        o[it] = __builtin_amdgcn_mfma_f32_16x16x32_bf16(pfh[it][ks], vfl[ks], o[it], 0,0,0);
      }
    const int n = vc*64 + w*16 + lr;
    #pragma unroll
    for (int it=0;it<3;it++){
      const size_t off = ((size_t)b*NN + n)*DD + h*48 + it*16 + g*4;
      u16x4 hv, lv;
      #pragma unroll
      for (int r=0;r<4;r++){
        float x = o[it][r];
        unsigned short hh = f2bf(x);
        hv[r] = hh; lv[r] = f2bf(x - bf2f(hh));
      }
      *(u16x4*)(coh + off) = hv;
      *(u16x4*)(col + off) = lv;
    }
    __syncthreads();
  }
}

// ---------------- tiled fp32 GEMM (kept for small batched GEMMs) ----------------
template<bool AT_, bool BT_, bool BIAS_, bool RES_>
__global__ __launch_bounds__(256) void gemm64_kernel(const float* __restrict__ A,
    const float* __restrict__ Bm, const float* __restrict__ bias,
    const float* __restrict__ res, float* __restrict__ Cc,
    int M, int Nd, int K, size_t sA, size_t sB, size_t sC)
{
  A  += (size_t)blockIdx.z*sA;
  Bm += (size_t)blockIdx.z*sB;
  Cc += (size_t)blockIdx.z*sC;
  const float* resp = RES_ ? res + (size_t)blockIdx.z*sC : nullptr;
  const int m0 = blockIdx.y*64, n0 = blockIdx.x*64;
  const int t = threadIdx.x, tx = t&15, ty = t>>4;
  __shared__ float As[16][68];
  __shared__ float Bs[16][68];
  float acc[4][4];
  #pragma unroll
  for (int i=0;i<4;i++)
    #pragma unroll
    for (int j=0;j<4;j++) acc[i][j]=0.f;

  for (int k0=0;k0<K;k0+=16){
    if (!AT_){
      const int r = t>>2, c4 = t&3;
      float4 av = *(const float4*)(A + (size_t)(m0+r)*K + k0 + c4*4);
      As[c4*4+0][r]=av.x; As[c4*4+1][r]=av.y; As[c4*4+2][r]=av.z; As[c4*4+3][r]=av.w;
    } else {
      const int r = t>>4, c4 = t&15;
      float4 av = *(const float4*)(A + (size_t)(k0+r)*M + m0 + c4*4);
      *(float4*)&As[r][c4*4] = av;
    }
    if (!BT_){
      const int r = t>>4, c4 = t&15;
      float4 bv = *(const float4*)(Bm + (size_t)(k0+r)*Nd + n0 + c4*4);
      *(float4*)&Bs[r][c4*4] = bv;
    } else {
      const int r = t>>2, c4 = t&3;
      float4 bv = *(const float4*)(Bm + (size_t)(n0+r)*K + k0 + c4*4);
      Bs[c4*4+0][r]=bv.x; Bs[c4*4+1][r]=bv.y; Bs[c4*4+2][r]=bv.z; Bs[c4*4+3][r]=bv.w;
    }
    __syncthreads();
    #pragma unroll
    for (int k=0;k<16;k++){
      const float4 a4 = *(const float4*)&As[k][ty*4];
      const float4 b4 = *(const float4*)&Bs[k][tx*4];
      float a_[4] = {a4.x,a4.y,a4.z,a4.w};
      float b_[4] = {b4.x,b4.y,b4.z,b4.w};
      #pragma unroll
      for (int i=0;i<4;i++)
        #pragma unroll
        for (int j=0;j<4;j++) acc[i][j] += a_[i]*b_[j];
    }
    __syncthreads();
  }
  float bv_[4];
  if (BIAS_){
    #pragma unroll
    for (int j=0;j<4;j++) bv_[j] = bias[n0 + tx*4 + j];
  }
  #pragma unroll
  for (int i=0;i<4;i++){
    const size_t row = (size_t)(m0 + ty*4 + i);
    float* Crow = Cc + row*Nd + n0 + tx*4;
    const float* Rrow = RES_ ? (resp + row*Nd + n0 + tx*4) : nullptr;
    #pragma unroll
    for (int j=0;j<4;j++){
      float v = acc[i][j];
      if (BIAS_) v += bv_[j];
      if (RES_)  v += Rrow[j];
      Crow[j] = v;
    }
  }
}

// ---------------- weight prep: transpose [K,N] -> bf16 hi/lo [N][K] ----------------
__global__ __launch_bounds__(256) void wconv_t_kernel(const float* __restrict__ in,
    unsigned short* __restrict__ oh, unsigned short* __restrict__ ol, int K, int N){
  __shared__ float tile[32][33];
  const int n0 = blockIdx.x*32, k0 = blockIdx.y*32;
  const int j = threadIdx.x & 31, i4 = threadIdx.x >> 5;
  #pragma unroll
  for (int s=0;s<4;s++){
    int i = i4*4+s;
    tile[i][j] = in[(size_t)(k0+i)*N + n0 + j];
  }
  __syncthreads();
  #pragma unroll
  for (int s=0;s<4;s++){
    int i = i4*4+s;
    float x = tile[j][i];                       // in[k0+j][n0+i]
    unsigned short h = f2bf(x);
    oh[(size_t)(n0+i)*K + k0 + j] = h;
    ol[(size_t)(n0+i)*K + k0 + j] = f2bf(x - bf2f(h));
  }
}

// ---------------- elementwise split fp32 -> bf16 hi/lo ----------------
__global__ __launch_bounds__(256) void wconv_kernel(const float* __restrict__ in,
    unsigned short* __restrict__ oh, unsigned short* __restrict__ ol, int n){
  int i = blockIdx.x*256 + threadIdx.x;
  if (i < n){
    float x = in[i];
    unsigned short h = f2bf(x);
    oh[i] = h;
    ol[i] = f2bf(x - bf2f(h));
  }
}

// ---------------- bf16x3 MFMA GEMM, pre-split A/B, 2-phase prefetch pipeline -----
// C[M,N] = A (bf16 hi/lo [M][K]) * B (bf16 hi/lo [N][K]) (+bias)(+res)
// 128x128 tile, BK=32, 4 waves. LDS [128][32] u16, 16B-block swizzle
//   blk_store = blk ^ ((row>>1)&3)  -> both ds_write_b128 and ds_read_b128
//   hit 8 distinct bank-quads per 16-lane phase (<=2-way, free).
// Pipeline: LOAD(t+1) issued before COMPUTE(t); WRITE after barrier.
template<bool BIAS_, bool RES_>
__global__ __launch_bounds__(256) void gemm_bf16x3s_kernel(
    const unsigned short* __restrict__ Ah, const unsigned short* __restrict__ Al,
    const unsigned short* __restrict__ Bh, const unsigned short* __restrict__ Bl,
    const float* __restrict__ bias, const float* __restrict__ res,
    float* __restrict__ C, int M, int N, int K)
{
  const int t = threadIdx.x;
  const int nwg = gridDim.x*gridDim.y;
  const int lin = blockIdx.y*gridDim.x + blockIdx.x;
  const int swz = (lin & 7)*(nwg >> 3) + (lin >> 3);
  const int bx = swz % gridDim.x, by = swz / gridDim.x;
  const int m0 = by*128, n0 = bx*128;

  __shared__ unsigned short As_h[128][32];
  __shared__ unsigned short As_l[128][32];
  __shared__ unsigned short Bs_h[128][32];
  __shared__ unsigned short Bs_l[128][32];

  const unsigned short* Ahb = Ah + (size_t)m0*K;
  const unsigned short* Alb = Al + (size_t)m0*K;
  const unsigned short* Bhb = Bh + (size_t)n0*K;
  const unsigned short* Blb = Bl + (size_t)n0*K;

  f32x4v acc[4][4];
  #pragma unroll
  for (int i=0;i<4;i++)
    #pragma unroll
    for (int j=0;j<4;j++) acc[i][j] = (f32x4v){0.f,0.f,0.f,0.f};

  const int w  = t >> 6;
  const int wm = w >> 1, wn = w & 1;
  const int lr = t & 15, g = (t & 63) >> 4;
  const int srow = t >> 1;                 // staging row (2 lanes/row)
  const int kb0  = (t & 1)*2;              // staging k-blocks {0,1} or {2,3}
  const int ssw  = (srow >> 1) & 3;        // store swizzle for this row
  const int ks0  = ((kb0+0) ^ ssw)*8;
  const int ks1  = ((kb0+1) ^ ssw)*8;

  uint4 rAh0,rAh1,rAl0,rAl1,rBh0,rBh1,rBl0,rBl1;

#define LOADT(K0) { \
    const size_t go0 = (size_t)srow*K + (K0) + (kb0+0)*8; \
    const size_t go1 = (size_t)srow*K + (K0) + (kb0+1)*8; \
    rAh0 = *(const uint4*)(Ahb + go0); rAh1 = *(const uint4*)(Ahb + go1); \
    rAl0 = *(const uint4*)(Alb + go0); rAl1 = *(const uint4*)(Alb + go1); \
    rBh0 = *(const uint4*)(Bhb + go0); rBh1 = *(const uint4*)(Bhb + go1); \
    rBl0 = *(const uint4*)(Blb + go0); rBl1 = *(const uint4*)(Blb + go1); }

#define WRITET() { \
    *(uint4*)&As_h[srow][ks0] = rAh0; *(uint4*)&As_h[srow][ks1] = rAh1; \
    *(uint4*)&As_l[srow][ks0] = rAl0; *(uint4*)&As_l[srow][ks1] = rAl1; \
    *(uint4*)&Bs_h[srow][ks0] = rBh0; *(uint4*)&Bs_h[srow][ks1] = rBh1; \
    *(uint4*)&Bs_l[srow][ks0] = rBl0; *(uint4*)&Bs_l[srow][ks1] = rBl1; }

#define COMPUTET() { \
    bf16x8 ah[4], al[4], bhf[4], blf[4]; \
    _Pragma("unroll") \
    for (int i=0;i<4;i++){ \
      const int ra = wm*64 + i*16 + lr; \
      const int ka = (g ^ ((ra>>1)&3))*8; \
      ah[i]  = *(const bf16x8*)&As_h[ra][ka]; \
      al[i]  = *(const bf16x8*)&As_l[ra][ka]; \
      const int rb = wn*64 + i*16 + lr; \
      const int kb = (g ^ ((rb>>1)&3))*8; \
      bhf[i] = *(const bf16x8*)&Bs_h[rb][kb]; \
      blf[i] = *(const bf16x8*)&Bs_l[rb][kb]; \
    } \
    _Pragma("unroll") \
    for (int mi=0;mi<4;mi++) \
      _Pragma("unroll") \
      for (int ni=0;ni<4;ni++){ \
        f32x4v c_ = acc[mi][ni]; \
        c_ = __builtin_amdgcn_mfma_f32_16x16x32_bf16(ah[mi], bhf[ni], c_, 0,0,0); \
        c_ = __builtin_amdgcn_mfma_f32_16x16x32_bf16(al[mi], bhf[ni], c_, 0,0,0); \
        c_ = __builtin_amdgcn_mfma_f32_16x16x32_bf16(ah[mi], blf[ni], c_, 0,0,0); \
        acc[mi][ni] = c_; \
      } }

  const int nk = K >> 5;
  LOADT(0);
  WRITET();
  for (int kt=1; kt<nk; kt++){
    __syncthreads();          // tile (kt-1) visible
    LOADT(kt*32);             // issue next-tile loads; latency hides under MFMA
    COMPUTET();               // compute tile (kt-1)
    __syncthreads();          // all reads done
    WRITET();                 // write tile kt (vmcnt drain here, not mid-loop)
  }
  __syncthreads();
  COMPUTET();                 // last tile

#undef LOADT
#undef WRITET
#undef COMPUTET

  #pragma unroll
  for (int ni=0;ni<4;ni++){
    const int col = n0 + wn*64 + ni*16 + lr;
    const float bb = BIAS_ ? bias[col] : 0.f;
    #pragma unroll
    for (int mi=0;mi<4;mi++){
      const int r0 = m0 + wm*64 + mi*16 + g*4;
      #pragma unroll
      for (int r=0;r<4;r++){
        float v = acc[mi][ni][r] + bb;
        if (RES_) v += res[(size_t)(r0+r)*N + col];
        C[(size_t)(r0+r)*N + col] = v;
      }
    }
  }
}

// ---------------- LN(rep) + concat residual -> tx ----------------
__global__ __launch_bounds__(256) void ln_concat_kernel(const float* __restrict__ rep,
    const float* __restrict__ g, const float* __restrict__ b,
    const float* __restrict__ ch1, const float* __restrict__ ch2,
    float* __restrict__ tx){
  const int row = blockIdx.x;
  const float* x = rep + (size_t)row*D2;
  float s=0.f;
  for (int i=threadIdx.x;i<D2;i+=256) s += x[i];
  s = blockReduceSum256(s);
  const float mu = s / (float)D2;
  float v=0.f;
  for (int i=threadIdx.x;i<D2;i+=256){ float d = x[i]-mu; v += d*d; }
  v = blockReduceSum256(v);
  const float rs = rsqrtf(v/(float)D2 + 1e-5f);
  float* o = tx + (size_t)row*D2;
  for (int i=threadIdx.x;i<D2;i+=256){
    float val = (x[i]-mu)*rs*g[i] + b[i];
    float rv = (i<DD) ? ch1[(size_t)row*DD + i] : ch2[(size_t)row*DD + i - DD];
    o[i] = val + rv;
  }
}

// ---------------- depthwise 3x3 conv + bias + exact GELU (split bf16 out) --------
__global__ __launch_bounds__(256) void dwconv_gelu_kernel(const float* __restrict__ h1,
    const float* __restrict__ w, const float* __restrict__ bias,
    unsigned short* __restrict__ gh, unsigned short* __restrict__ gl){
  const int idx = blockIdx.x*256 + threadIdx.x;   // 16*32*384 = 196608 total
  const int b   = idx / 12288;                    // 12288 = 32*384 (uniform per block)
  const int r   = idx - b*12288;
  const int hh  = r / 384;
  const int c4  = r - hh*384;
  const int c   = c4*4;
  const float* base = h1 + (size_t)b*NN*C2 + c;
  const size_t obase = ((size_t)b*NN + hh*32)*C2 + c;

  f32x4v wk[9];
  #pragma unroll
  for (int k=0;k<9;k++){
    f32x4v t_;
    #pragma unroll
    for (int q=0;q<4;q++) t_[q] = w[(size_t)(c+q)*9 + k];
    wk[k] = t_;
  }
  f32x4v bvv;
  {
    const float4 bb = *(const float4*)(bias + c);
    bvv = (f32x4v){bb.x, bb.y, bb.z, bb.w};
  }

  const bool hm = (hh > 0), hp = (hh < 31);
  const f32x4v z4 = (f32x4v){0.f,0.f,0.f,0.f};
  const size_t rm = (size_t)((hh-1)*32)*C2;
  const size_t r0 = (size_t)( hh   *32)*C2;
  const size_t rp = (size_t)((hh+1)*32)*C2;

  f32x4v A0,A1,A2, B0,B1,B2, C0,C1,C2c;
  A0=z4; A1=z4; A2=z4;
  B0 = hm ? *(const f32x4v*)(base + rm) : z4;
  B1 =      *(const f32x4v*)(base + r0);
  B2 = hp ? *(const f32x4v*)(base + rp) : z4;
  C0 = hm ? *(const f32x4v*)(base + rm + C2) : z4;
  C1 =      *(const f32x4v*)(base + r0 + C2);
  C2c= hp ? *(const f32x4v*)(base + rp + C2) : z4;

  for (int ww=0; ww<32; ww++){
    f32x4v N0,N1,N2;
    if (ww < 30){
      const size_t co_ = (size_t)(ww+2)*C2;
      N0 = hm ? *(const f32x4v*)(base + rm + co_) : z4;
      N1 =      *(const f32x4v*)(base + r0 + co_) ;
      N2 = hp ? *(const f32x4v*)(base + rp + co_) : z4;
    } else { N0=z4; N1=z4; N2=z4; }

    f32x4v s = bvv;
    s += wk[0]*A0 + wk[1]*B0 + wk[2]*C0;
    s += wk[3]*A1 + wk[4]*B1 + wk[5]*C1;
    s += wk[6]*A2 + wk[7]*B2 + wk[8]*C2c;

    u16x4 hv, lv;
    #pragma unroll
    for (int q=0;q<4;q++){
      float rlt = 0.5f*s[q]*(1.f + erff(s[q]*0.70710678118654752f));
      unsigned short hhv = f2bf(rlt);
      hv[q] = hhv; lv[q] = f2bf(rlt - bf2f(hhv));
    }
    *(u16x4*)(gh + obase + (size_t)ww*C2) = hv;
    *(u16x4*)(gl + obase + (size_t)ww*C2) = lv;

    A0=B0; A1=B1; A2=B2;
    B0=C0; B1=C1; B2=C2c;
    C0=N0; C1=N1; C2c=N2;
  }
}

// ---------------- launch ----------------
extern "C" void kernel_launch(void* const* d_in, const int* in_sizes, int n_in,
                              void* d_out, int out_size, void* d_ws, size_t ws_size,
                              hipStream_t stream) {
  const float* x1     = (const float*)d_in[0];
  const float* x2     = (const float*)d_in[1];
  const float* ln1_g  = (const float*)d_in[2];
  const float* ln1_b  = (const float*)d_in[3];
  const float* qkv_w  = (const float*)d_in[4];
  const float* ca_temp= (const float*)d_in[5];
  const float* proj_w = (const float*)d_in[6];
  const float* proj_b = (const float*)d_in[7];
  const float* ln3_g  = (const float*)d_in[8];
  const float* ln3_b  = (const float*)d_in[9];
  const float* rp_w   = (const float*)d_in[10];
  const float* rp_b   = (const float*)d_in[11];
  const float* cn_g   = (const float*)d_in[12];
  const float* cn_b   = (const float*)d_in[13];
  const float* ln2_g  = (const float*)d_in[14];
  const float* ln2_b  = (const float*)d_in[15];
  const float* fc1_w  = (const float*)d_in[16];
  const float* fc1_b  = (const float*)d_in[17];
  const float* dw_w   = (const float*)d_in[18];
  const float* dw_b   = (const float*)d_in[19];
  const float* fc2_w  = (const float*)d_in[20];
  const float* fc2_b  = (const float*)d_in[21];
  float* out = (float*)d_out;
  float* W   = (float*)d_ws;

  // ---- workspace layout (peak 50,331,648 floats = 192 MiB) ----
  unsigned short* ycoh = (unsigned short*)W;        // SZ_ND u16
  unsigned short* ycol = ycoh + (size_t)SZ_ND;      // SZ_ND u16 (region = SZ_ND floats)
  unsigned short* coh  = ycoh;                      // reuse after qkv GEMM
  unsigned short* col  = ycol;
  float* qkvb = W + (size_t)SZ_ND;
  float* ch1  = W + 25165824ull;
  float* ch2  = W + 31457280ull;
  unsigned short* qkvwT_h  = (unsigned short*)(W + 37748736ull);
  unsigned short* qkvwT_l  = qkvwT_h + 442368u;
  unsigned short* projwT_h = qkvwT_l + 442368u;
  unsigned short* projwT_l = projwT_h + 147456u;
  float* n1  = W;
  float* n2  = W + (size_t)SZ_ND;
  float* KS  = W + 2ull*SZ_ND;
  float* QS  = W + 3ull*SZ_ND;
  float* ctx = W + (size_t)SZ_ND;
  float* ATb = W;
  unsigned short* ATbh = (unsigned short*)(W + 3ull*SZ_ND);
  unsigned short* ATbl = ATbh + (size_t)SZ_ND;
  float* rep = W + (size_t)SZ_ND;
  unsigned short* rpw_h = (unsigned short*)(W + 37748736ull);
  unsigned short* rpw_l = rpw_h + 294912u;
  float* txp  = out;
  float* h1   = W;
  unsigned short* y2h = (unsigned short*)(W + 25165824ull);
  unsigned short* y2l = y2h + (size_t)SZ_N2D;
  unsigned short* fc1wT_h = (unsigned short*)(W + 37748736ull);
  unsigned short* fc1wT_l = fc1wT_h + 1179648u;
  unsigned short* gh = (unsigned short*)(W + 25165824ull);
  unsigned short* gl = gh + (size_t)SZ_NC2;
  unsigned short* fc2wT_h = (unsigned short*)W;
  unsigned short* fc2wT_l = fc2wT_h + 1179648u;

  const int M = BN*NN;

  // ---- phase-A weight prep ----
  wconv_t_kernel<<<dim3(1152/32, DD/32), dim3(256), 0, stream>>>(qkv_w, qkvwT_h, qkvwT_l, DD, 1152);
  wconv_t_kernel<<<dim3(DD/32, DD/32), dim3(256), 0, stream>>>(proj_w, projwT_h, projwT_l, DD, DD);

  // ---- channel attention, stream 1 ----
  ln_split_kernel<<<dim3(M), dim3(256), 0, stream>>>(x1, ln1_g, ln1_b, ycoh, ycol, DD);
  gemm_bf16x3s_kernel<false,false><<<dim3(1152/128, M/128), dim3(256), 0, stream>>>(
      ycoh, ycol, qkvwT_h, qkvwT_l, nullptr, nullptr, qkvb, M, 1152, DD);
  chattn_mfma_kernel<<<dim3(BN*NHEAD), dim3(256), 0, stream>>>(qkvb, ca_temp, coh, col);
  gemm_bf16x3s_kernel<true,true><<<dim3(DD/128, M/128), dim3(256), 0, stream>>>(
      coh, col, projwT_h, projwT_l, proj_b, x1, ch1, M, DD, DD);

  // ---- channel attention, stream 2 ----
  ln_split_kernel<<<dim3(M), dim3(256), 0, stream>>>(x2, ln1_g, ln1_b, ycoh, ycol, DD);
  gemm_bf16x3s_kernel<false,false><<<dim3(1152/128, M/128), dim3(256), 0, stream>>>(
      ycoh, ycol, qkvwT_h, qkvwT_l, nullptr, nullptr, qkvb, M, 1152, DD);
  chattn_mfma_kernel<<<dim3(BN*NHEAD), dim3(256), 0, stream>>>(qkvb, ca_temp, coh, col);
  gemm_bf16x3s_kernel<true,true><<<dim3(DD/128, M/128), dim3(256), 0, stream>>>(
      coh, col, projwT_h, projwT_l, proj_b, x2, ch2, M, DD, DD);

  // ---- cross attention ----
  wconv_kernel<<<dim3(294912/256), dim3(256), 0, stream>>>(rp_w, rpw_h, rpw_l, 294912);
  ln_kernel<<<dim3(M), dim3(256), 0, stream>>>(ch1, ln3_g, ln3_b, n1, DD);
  ln_kernel<<<dim3(M), dim3(256), 0, stream>>>(ch2, ln3_g, ln3_b, n2, DD);
  rowsoftmax_kernel<<<dim3(M), dim3(256), 0, stream>>>(n2, QS, DD);
  colsoftmax_kernel<<<dim3(DD/64, BN), dim3(256), 0, stream>>>(n2, KS);
  gemm64_kernel<true,false,false,false><<<dim3(DD/64, DD/64, BN), dim3(256), 0, stream>>>(
      KS, n1, nullptr, nullptr, ctx, DD, DD, NN,
      (size_t)NN*DD, (size_t)NN*DD, (size_t)DD*DD);
  gemm64_kernel<false,false,false,false><<<dim3(DD/64, NN/64, BN), dim3(256), 0, stream>>>(
      QS, ctx, nullptr, nullptr, ATb, NN, DD, DD,
      (size_t)NN*DD, (size_t)DD*DD, (size_t)NN*DD);
  wconv_kernel<<<dim3(SZ_ND/256), dim3(256), 0, stream>>>(ATb, ATbh, ATbl, SZ_ND);
  gemm_bf16x3s_kernel<true,false><<<dim3(D2/128, M/128), dim3(256), 0, stream>>>(
      ATbh, ATbl, rpw_h, rpw_l, rp_b, nullptr, rep, M, D2, DD);
  ln_concat_kernel<<<dim3(M), dim3(256), 0, stream>>>(rep, cn_g, cn_b, ch1, ch2, txp);

  // ---- mix FFN ----
  wconv_t_kernel<<<dim3(C2/32, D2/32), dim3(256), 0, stream>>>(fc1_w, fc1wT_h, fc1wT_l, D2, C2);
  ln_split_kernel<<<dim3(M), dim3(256), 0, stream>>>(txp, ln2_g, ln2_b, y2h, y2l, D2);
  gemm_bf16x3s_kernel<true,false><<<dim3(C2/128, M/128), dim3(256), 0, stream>>>(
      y2h, y2l, fc1wT_h, fc1wT_l, fc1_b, nullptr, h1, M, C2, D2);
  dwconv_gelu_kernel<<<dim3(196608/256), dim3(256), 0, stream>>>(h1, dw_w, dw_b, gh, gl);
  wconv_t_kernel<<<dim3(D2/32, C2/32), dim3(256), 0, stream>>>(fc2_w, fc2wT_h, fc2wT_l, C2, D2);
  gemm_bf16x3s_kernel<true,true><<<dim3(D2/128, M/128), dim3(256), 0, stream>>>(
      gh, gl, fc2wT_h, fc2wT_l, fc2_b, txp, out, M, D2, C2);
}

// Round 6
// 1067.330 us; speedup vs baseline: 1.1936x; 1.0472x over previous
//
#include <hip/hip_runtime.h>
#include <math.h>

#define BN 16
#define NN 1024
#define DD 384
#define D2 768
#define C2 1536
#define NHEAD 8
#define DH 48

#define SZ_ND   (BN*NN*DD)      /* 6291456  */
#define SZ_N2D  (BN*NN*D2)      /* 12582912 */
#define SZ_NC2  (BN*NN*C2)      /* 25165824 */
#define SZ_QKV  (BN*NN*3*DD)    /* 18874368 */

typedef __bf16 bf16x8 __attribute__((ext_vector_type(8)));
typedef float f32x4v __attribute__((ext_vector_type(4)));
typedef unsigned short u16x4 __attribute__((ext_vector_type(4)));

__device__ __forceinline__ unsigned short f2bf(float x){
  unsigned int u = __float_as_uint(x);
  u += 0x7FFFu + ((u >> 16) & 1u);          // round-nearest-even to bf16
  return (unsigned short)(u >> 16);
}
__device__ __forceinline__ float bf2f(unsigned short h){
  return __uint_as_float(((unsigned int)h) << 16);
}

// ---------------- block reductions (256 threads = 4 waves) ----------------
__device__ __forceinline__ float blockReduceSum256(float v){
  __shared__ float red[4];
  #pragma unroll
  for (int o=32;o;o>>=1) v += __shfl_down(v,o,64);
  if ((threadIdx.x&63)==0) red[threadIdx.x>>6]=v;
  __syncthreads();
  float r = red[0]+red[1]+red[2]+red[3];
  __syncthreads();
  return r;
}
__device__ __forceinline__ float blockReduceMax256(float v){
  __shared__ float red[4];
  #pragma unroll
  for (int o=32;o;o>>=1) v = fmaxf(v, __shfl_down(v,o,64));
  if ((threadIdx.x&63)==0) red[threadIdx.x>>6]=v;
  __syncthreads();
  float r = fmaxf(fmaxf(red[0],red[1]),fmaxf(red[2],red[3]));
  __syncthreads();
  return r;
}

// ---------------- LayerNorm: one block per row (fp32 out) ----------------
__global__ __launch_bounds__(256) void ln_kernel(const float* __restrict__ in,
    const float* __restrict__ g, const float* __restrict__ b,
    float* __restrict__ out, int C){
  const int row = blockIdx.x;
  const float* x = in + (size_t)row*C;
  float s=0.f;
  for (int i=threadIdx.x;i<C;i+=256) s += x[i];
  s = blockReduceSum256(s);
  const float mu = s / (float)C;
  float v=0.f;
  for (int i=threadIdx.x;i<C;i+=256){ float d = x[i]-mu; v += d*d; }
  v = blockReduceSum256(v);
  const float rs = rsqrtf(v/(float)C + 1e-5f);
  float* o = out + (size_t)row*C;
  for (int i=threadIdx.x;i<C;i+=256) o[i] = (x[i]-mu)*rs*g[i] + b[i];
}

// ---------------- LayerNorm with bf16 hi/lo split output ----------------
__global__ __launch_bounds__(256) void ln_split_kernel(const float* __restrict__ in,
    const float* __restrict__ g, const float* __restrict__ b,
    unsigned short* __restrict__ oh, unsigned short* __restrict__ ol, int C){
  const int row = blockIdx.x;
  const float* x = in + (size_t)row*C;
  float s=0.f;
  for (int i=threadIdx.x;i<C;i+=256) s += x[i];
  s = blockReduceSum256(s);
  const float mu = s / (float)C;
  float v=0.f;
  for (int i=threadIdx.x;i<C;i+=256){ float d = x[i]-mu; v += d*d; }
  v = blockReduceSum256(v);
  const float rs = rsqrtf(v/(float)C + 1e-5f);
  unsigned short* ohp = oh + (size_t)row*C;
  unsigned short* olp = ol + (size_t)row*C;
  for (int i=threadIdx.x;i<C;i+=256){
    float val = (x[i]-mu)*rs*g[i] + b[i];
    unsigned short hh = f2bf(val);
    ohp[i] = hh; olp[i] = f2bf(val - bf2f(hh));
  }
}

// ---------------- row softmax (QS: softmax over channels d) ----------------
__global__ __launch_bounds__(256) void rowsoftmax_kernel(const float* __restrict__ in,
    float* __restrict__ out, int C){
  const int row = blockIdx.x;
  const float* x = in + (size_t)row*C;
  float m = -3.0e38f;
  for (int i=threadIdx.x;i<C;i+=256) m = fmaxf(m, x[i]);
  m = blockReduceMax256(m);
  float s = 0.f;
  for (int i=threadIdx.x;i<C;i+=256) s += expf(x[i]-m);
  s = blockReduceSum256(s);
  const float inv = 1.f/s;
  float* o = out + (size_t)row*C;
  for (int i=threadIdx.x;i<C;i+=256) o[i] = expf(x[i]-m)*inv;
}

// ---------------- column softmax over tokens n (KS) ----------------
__global__ __launch_bounds__(256) void colsoftmax_kernel(const float* __restrict__ in,
    float* __restrict__ out){
  const int dl = threadIdx.x & 63;
  const int nc = threadIdx.x >> 6;
  const int d  = blockIdx.x*64 + dl;
  const int b  = blockIdx.y;
  const float* p = in + (size_t)b*NN*DD + d;
  __shared__ float redm[4][64];
  __shared__ float reds[4][64];
  float m = -3.0e38f;
  for (int n=nc*256; n<nc*256+256; n++) m = fmaxf(m, p[(size_t)n*DD]);
  redm[nc][dl] = m; __syncthreads();
  m = fmaxf(fmaxf(redm[0][dl],redm[1][dl]),fmaxf(redm[2][dl],redm[3][dl]));
  float s=0.f;
  for (int n=nc*256;n<nc*256+256;n++) s += expf(p[(size_t)n*DD]-m);
  reds[nc][dl]=s; __syncthreads();
  s = reds[0][dl]+reds[1][dl]+reds[2][dl]+reds[3][dl];
  const float inv = 1.f/s;
  float* q = out + (size_t)b*NN*DD + d;
  for (int n=nc*256;n<nc*256+256;n++) q[(size_t)n*DD] = expf(p[(size_t)n*DD]-m)*inv;
}

// ---------------- channel attention, MFMA version (split bf16 output) ------------
__global__ __launch_bounds__(256) void chattn_mfma_kernel(
    const float* __restrict__ qkv, const float* __restrict__ temp,
    unsigned short* __restrict__ coh, unsigned short* __restrict__ col)
{
  const int bh = blockIdx.x, b = bh >> 3, h = bh & 7;
  const int t = threadIdx.x, w = t >> 6, lane = t & 63;
  const int lr = lane & 15, g = lane >> 4;

  __shared__ __align__(16) unsigned char ldsA[27648];
  unsigned short (*Qh)[72] = (unsigned short(*)[72])(ldsA);
  unsigned short (*Ql)[72] = (unsigned short(*)[72])(ldsA + 6912);
  unsigned short (*Kh)[72] = (unsigned short(*)[72])(ldsA + 13824);
  unsigned short (*Kl)[72] = (unsigned short(*)[72])(ldsA + 20736);
  unsigned short (*Vh)[72] = (unsigned short(*)[72])(ldsA);
  unsigned short (*Vl)[72] = (unsigned short(*)[72])(ldsA + 9216);
  __shared__ unsigned short Ph[48][72], Pl[48][72];
  __shared__ float S[48][49];
  __shared__ float qn[48], kn[48];

  const size_t base = (size_t)b*NN*1152 + (size_t)h*48;

  int agrp[3], apr[3], aoff[3];
  #pragma unroll
  for (int l=0;l<3;l++){
    int idx = l*256+t;
    int mo = (idx>=384) ? 1 : 0;
    int a = idx - mo*384;
    agrp[l] = a%12; apr[l] = a/12; aoff[l] = mo*384;
  }

  f32x4v acc[12];
  #pragma unroll
  for (int i=0;i<12;i++) acc[i] = (f32x4v){0.f,0.f,0.f,0.f};

  float4 cur[3][2];
  #pragma unroll
  for (int l=0;l<3;l++){
    const float* p = qkv + base + (size_t)(apr[l]*2)*1152 + aoff[l] + agrp[l]*4;
    cur[l][0] = *(const float4*)p;
    cur[l][1] = *(const float4*)(p+1152);
  }

  for (int nc=0; nc<16; nc++){
    #pragma unroll
    for (int l=0;l<3;l++){
      unsigned short (*Dh)[72] = aoff[l] ? Kh : Qh;
      unsigned short (*Dl)[72] = aoff[l] ? Kl : Ql;
      const float x0[4] = {cur[l][0].x, cur[l][0].y, cur[l][0].z, cur[l][0].w};
      const float x1[4] = {cur[l][1].x, cur[l][1].y, cur[l][1].z, cur[l][1].w};
      #pragma unroll
      for (int c=0;c<4;c++){
        int d = agrp[l]*4+c;
        unsigned short h0 = f2bf(x0[c]), h1 = f2bf(x1[c]);
        unsigned short l0 = f2bf(x0[c]-bf2f(h0)), l1 = f2bf(x1[c]-bf2f(h1));
        *(unsigned int*)&Dh[d][apr[l]*2] = (unsigned)h0 | ((unsigned)h1<<16);
        *(unsigned int*)&Dl[d][apr[l]*2] = (unsigned)l0 | ((unsigned)l1<<16);
      }
    }
    __syncthreads();
    if (nc < 15){
      #pragma unroll
      for (int l=0;l<3;l++){
        const float* p = qkv + base + (size_t)((nc+1)*64 + apr[l]*2)*1152 + aoff[l] + agrp[l]*4;
        cur[l][0] = *(const float4*)p;
        cur[l][1] = *(const float4*)(p+1152);
      }
    }
    if (w < 3){
      #pragma unroll
      for (int ks=0;ks<2;ks++){
        bf16x8 a_h = *(const bf16x8*)&Qh[w*16+lr][ks*32+g*8];
        bf16x8 a_l = *(const bf16x8*)&Ql[w*16+lr][ks*32+g*8];
        #pragma unroll
        for (int c=0;c<3;c++){
          bf16x8 b_h = *(const bf16x8*)&Kh[c*16+lr][ks*32+g*8];
          bf16x8 b_l = *(const bf16x8*)&Kl[c*16+lr][ks*32+g*8];
          acc[c] = __builtin_amdgcn_mfma_f32_16x16x32_bf16(a_h, b_h, acc[c], 0,0,0);
          acc[c] = __builtin_amdgcn_mfma_f32_16x16x32_bf16(a_l, b_h, acc[c], 0,0,0);
          acc[c] = __builtin_amdgcn_mfma_f32_16x16x32_bf16(a_h, b_l, acc[c], 0,0,0);
        }
      }
    } else {
      #pragma unroll
      for (int ks=0;ks<2;ks++){
        #pragma unroll
        for (int c=0;c<3;c++){
          bf16x8 qh_ = *(const bf16x8*)&Qh[c*16+lr][ks*32+g*8];
          bf16x8 ql_ = *(const bf16x8*)&Ql[c*16+lr][ks*32+g*8];
          bf16x8 kh_ = *(const bf16x8*)&Kh[c*16+lr][ks*32+g*8];
          bf16x8 kl_ = *(const bf16x8*)&Kl[c*16+lr][ks*32+g*8];
          acc[c]   = __builtin_amdgcn_mfma_f32_16x16x32_bf16(qh_, qh_, acc[c],   0,0,0);
          acc[3+c] = __builtin_amdgcn_mfma_f32_16x16x32_bf16(qh_, ql_, acc[3+c], 0,0,0);
          acc[6+c] = __builtin_amdgcn_mfma_f32_16x16x32_bf16(kh_, kh_, acc[6+c], 0,0,0);
          acc[9+c] = __builtin_amdgcn_mfma_f32_16x16x32_bf16(kh_, kl_, acc[9+c], 0,0,0);
        }
      }
    }
    __syncthreads();
  }

  const float tp = temp[h];
  if (w == 3){
    if ((lane>>4) == ((lane&15)>>2)){
      int p = lane & 15, r = p & 3;
      #pragma unroll
      for (int c=0;c<3;c++){
        float q2 = fmaxf(acc[c][r]   + 2.f*acc[3+c][r], 0.f);
        float k2 = fmaxf(acc[6+c][r] + 2.f*acc[9+c][r], 0.f);
        qn[c*16+p] = fmaxf(sqrtf(q2), 1e-12f);
        kn[c*16+p] = fmaxf(sqrtf(k2), 1e-12f);
      }
    }
  }
  __syncthreads();
  if (w < 3){
    #pragma unroll
    for (int c=0;c<3;c++){
      #pragma unroll
      for (int r=0;r<4;r++){
        int i = w*16 + g*4 + r, j = c*16 + lr;
        S[i][j] = acc[c][r]*tp/(qn[i]*kn[j]);
      }
    }
  }
  __syncthreads();

  int vgrp[3], vtk[3];
  #pragma unroll
  for (int l=0;l<3;l++){ int idx=l*256+t; vtk[l]=idx/12; vgrp[l]=idx%12; }
  float4 pv[3];
  #pragma unroll
  for (int l=0;l<3;l++)
    pv[l] = *(const float4*)(qkv + base + (size_t)vtk[l]*1152 + 768 + vgrp[l]*4);

  if (t < 48){
    float m = -3.0e38f;
    for (int j=0;j<48;j++) m = fmaxf(m, S[t][j]);
    float s = 0.f;
    for (int j=0;j<48;j++){ float e_ = expf(S[t][j]-m); S[t][j] = e_; s += e_; }
    float inv = 1.f/s;
    for (int j=0;j<48;j++){
      float p = S[t][j]*inv;
      unsigned short hp = f2bf(p);
      Ph[t][j] = hp; Pl[t][j] = f2bf(p - bf2f(hp));
    }
    #pragma unroll
    for (int j=48;j<64;j++){ Ph[t][j]=0; Pl[t][j]=0; }
  } else {
    const u16x4 z4 = (u16x4){0,0,0,0};
    for (int idx=t-48; idx<512; idx+=208){
      int tk = idx>>3, q = idx&7;
      if (q<4) *(u16x4*)&Vh[tk][48+(q&3)*4] = z4;
      else     *(u16x4*)&Vl[tk][48+(q&3)*4] = z4;
    }
  }
  __syncthreads();

  bf16x8 pfh[3][2], pfl[3][2];
  #pragma unroll
  for (int it=0;it<3;it++)
    #pragma unroll
    for (int ks=0;ks<2;ks++){
      pfh[it][ks] = *(const bf16x8*)&Ph[it*16+lr][ks*32+g*8];
      pfl[it][ks] = *(const bf16x8*)&Pl[it*16+lr][ks*32+g*8];
    }

  for (int vc=0; vc<16; vc++){
    #pragma unroll
    for (int l=0;l<3;l++){
      const float xv[4] = {pv[l].x, pv[l].y, pv[l].z, pv[l].w};
      u16x4 hv, lv;
      #pragma unroll
      for (int c=0;c<4;c++){
        unsigned short hh = f2bf(xv[c]);
        hv[c] = hh; lv[c] = f2bf(xv[c] - bf2f(hh));
      }
      *(u16x4*)&Vh[vtk[l]][vgrp[l]*4] = hv;
      *(u16x4*)&Vl[vtk[l]][vgrp[l]*4] = lv;
    }
    __syncthreads();
    if (vc < 15){
      #pragma unroll
      for (int l=0;l<3;l++)
        pv[l] = *(const float4*)(qkv + base + (size_t)((vc+1)*64+vtk[l])*1152 + 768 + vgrp[l]*4);
    }
    bf16x8 vfh[2], vfl[2];
    #pragma unroll
    for (int ks=0;ks<2;ks++){
      vfh[ks] = *(const bf16x8*)&Vh[w*16+lr][ks*32+g*8];
      vfl[ks] = *(const bf16x8*)&Vl[w*16+lr][ks*32+g*8];
    }
    f32x4v o[3];
    #pragma unroll
    for (int it=0;it<3;it++) o[it] = (f32x4v){0.f,0.f,0.f,0.f};
    #pragma unroll
    for (int it=0;it<3;it++)
      #pragma unroll
      for (int ks=0;ks<2;ks++){
        o[it] = __builtin_amdgcn_mfma_f32_16x16x32_bf16(pfh[it][ks], vfh[ks], o[it], 0,0,0);
        o[it] = __builtin_amdgcn_mfma_f32_16x16x32_bf16(pfl[it][ks], vfh[ks], o[it], 0,0,0);
        o[it] = __builtin_amdgcn_mfma_f32_16x16x32_bf16(pfh[it][ks], vfl[ks], o[it], 0,0,0);
      }
    const int n = vc*64 + w*16 + lr;
    #pragma unroll
    for (int it=0;it<3;it++){
      const size_t off = ((size_t)b*NN + n)*DD + h*48 + it*16 + g*4;
      u16x4 hv, lv;
      #pragma unroll
      for (int r=0;r<4;r++){
        float x = o[it][r];
        unsigned short hh = f2bf(x);
        hv[r] = hh; lv[r] = f2bf(x - bf2f(hh));
      }
      *(u16x4*)(coh + off) = hv;
      *(u16x4*)(col + off) = lv;
    }
    __syncthreads();
  }
}

// ---------------- tiled fp32 GEMM (kept for small batched GEMMs) ----------------
template<bool AT_, bool BT_, bool BIAS_, bool RES_>
__global__ __launch_bounds__(256) void gemm64_kernel(const float* __restrict__ A,
    const float* __restrict__ Bm, const float* __restrict__ bias,
    const float* __restrict__ res, float* __restrict__ Cc,
    int M, int Nd, int K, size_t sA, size_t sB, size_t sC)
{
  A  += (size_t)blockIdx.z*sA;
  Bm += (size_t)blockIdx.z*sB;
  Cc += (size_t)blockIdx.z*sC;
  const float* resp = RES_ ? res + (size_t)blockIdx.z*sC : nullptr;
  const int m0 = blockIdx.y*64, n0 = blockIdx.x*64;
  const int t = threadIdx.x, tx = t&15, ty = t>>4;
  __shared__ float As[16][68];
  __shared__ float Bs[16][68];
  float acc[4][4];
  #pragma unroll
  for (int i=0;i<4;i++)
    #pragma unroll
    for (int j=0;j<4;j++) acc[i][j]=0.f;

  for (int k0=0;k0<K;k0+=16){
    if (!AT_){
      const int r = t>>2, c4 = t&3;
      float4 av = *(const float4*)(A + (size_t)(m0+r)*K + k0 + c4*4);
      As[c4*4+0][r]=av.x; As[c4*4+1][r]=av.y; As[c4*4+2][r]=av.z; As[c4*4+3][r]=av.w;
    } else {
      const int r = t>>4, c4 = t&15;
      float4 av = *(const float4*)(A + (size_t)(k0+r)*M + m0 + c4*4);
      *(float4*)&As[r][c4*4] = av;
    }
    if (!BT_){
      const int r = t>>4, c4 = t&15;
      float4 bv = *(const float4*)(Bm + (size_t)(k0+r)*Nd + n0 + c4*4);
      *(float4*)&Bs[r][c4*4] = bv;
    } else {
      const int r = t>>2, c4 = t&3;
      float4 bv = *(const float4*)(Bm + (size_t)(n0+r)*K + k0 + c4*4);
      Bs[c4*4+0][r]=bv.x; Bs[c4*4+1][r]=bv.y; Bs[c4*4+2][r]=bv.z; Bs[c4*4+3][r]=bv.w;
    }
    __syncthreads();
    #pragma unroll
    for (int k=0;k<16;k++){
      const float4 a4 = *(const float4*)&As[k][ty*4];
      const float4 b4 = *(const float4*)&Bs[k][tx*4];
      float a_[4] = {a4.x,a4.y,a4.z,a4.w};
      float b_[4] = {b4.x,b4.y,b4.z,b4.w};
      #pragma unroll
      for (int i=0;i<4;i++)
        #pragma unroll
        for (int j=0;j<4;j++) acc[i][j] += a_[i]*b_[j];
    }
    __syncthreads();
  }
  float bv_[4];
  if (BIAS_){
    #pragma unroll
    for (int j=0;j<4;j++) bv_[j] = bias[n0 + tx*4 + j];
  }
  #pragma unroll
  for (int i=0;i<4;i++){
    const size_t row = (size_t)(m0 + ty*4 + i);
    float* Crow = Cc + row*Nd + n0 + tx*4;
    const float* Rrow = RES_ ? (resp + row*Nd + n0 + tx*4) : nullptr;
    #pragma unroll
    for (int j=0;j<4;j++){
      float v = acc[i][j];
      if (BIAS_) v += bv_[j];
      if (RES_)  v += Rrow[j];
      Crow[j] = v;
    }
  }
}

// ---------------- weight prep: transpose [K,N] -> bf16 hi/lo [N][K] ----------------
__global__ __launch_bounds__(256) void wconv_t_kernel(const float* __restrict__ in,
    unsigned short* __restrict__ oh, unsigned short* __restrict__ ol, int K, int N){
  __shared__ float tile[32][33];
  const int n0 = blockIdx.x*32, k0 = blockIdx.y*32;
  const int j = threadIdx.x & 31, i4 = threadIdx.x >> 5;
  #pragma unroll
  for (int s=0;s<4;s++){
    int i = i4*4+s;
    tile[i][j] = in[(size_t)(k0+i)*N + n0 + j];
  }
  __syncthreads();
  #pragma unroll
  for (int s=0;s<4;s++){
    int i = i4*4+s;
    float x = tile[j][i];                       // in[k0+j][n0+i]
    unsigned short h = f2bf(x);
    oh[(size_t)(n0+i)*K + k0 + j] = h;
    ol[(size_t)(n0+i)*K + k0 + j] = f2bf(x - bf2f(h));
  }
}

// ---------------- elementwise split fp32 -> bf16 hi/lo ----------------
__global__ __launch_bounds__(256) void wconv_kernel(const float* __restrict__ in,
    unsigned short* __restrict__ oh, unsigned short* __restrict__ ol, int n){
  int i = blockIdx.x*256 + threadIdx.x;
  if (i < n){
    float x = in[i];
    unsigned short h = f2bf(x);
    oh[i] = h;
    ol[i] = f2bf(x - bf2f(h));
  }
}

// ---------------- bf16x3 MFMA GEMM: dbuf LDS + distance-2 prefetch ----------------
// C[M,N] = A (bf16 hi/lo [M][K]) * B (bf16 hi/lo [N][K]) (+bias)(+res)
// 128x128 tile, BK=32, 4 waves. LDS 2x [128][32] u16 per operand plane (64 KB),
// 16B-block swizzle blk^((row>>1)&3) (bank-conflict-free, verified R5: 0 conflicts).
// One barrier per K-step; register set in flight across ~2 COMPUTE phases so the
// auto vmcnt before ds_write waits on loads issued ~800+ cycles earlier.
// Requires K%64==0 (nk even) -- true for all call sites (K=384/768/1536).
template<bool BIAS_, bool RES_>
__global__ __launch_bounds__(256) void gemm_bf16x3s_kernel(
    const unsigned short* __restrict__ Ah, const unsigned short* __restrict__ Al,
    const unsigned short* __restrict__ Bh, const unsigned short* __restrict__ Bl,
    const float* __restrict__ bias, const float* __restrict__ res,
    float* __restrict__ C, int M, int N, int K)
{
  const int t = threadIdx.x;
  const int nwg = gridDim.x*gridDim.y;
  const int lin = blockIdx.y*gridDim.x + blockIdx.x;
  const int swz = (lin & 7)*(nwg >> 3) + (lin >> 3);
  const int bx = swz % gridDim.x, by = swz / gridDim.x;
  const int m0 = by*128, n0 = bx*128;

  __shared__ unsigned short As_h0[128][32], As_l0[128][32];
  __shared__ unsigned short Bs_h0[128][32], Bs_l0[128][32];
  __shared__ unsigned short As_h1[128][32], As_l1[128][32];
  __shared__ unsigned short Bs_h1[128][32], Bs_l1[128][32];

  const unsigned short* Ahb = Ah + (size_t)m0*K;
  const unsigned short* Alb = Al + (size_t)m0*K;
  const unsigned short* Bhb = Bh + (size_t)n0*K;
  const unsigned short* Blb = Bl + (size_t)n0*K;

  f32x4v acc[4][4];
  #pragma unroll
  for (int i=0;i<4;i++)
    #pragma unroll
    for (int j=0;j<4;j++) acc[i][j] = (f32x4v){0.f,0.f,0.f,0.f};

  const int w  = t >> 6;
  const int wm = w >> 1, wn = w & 1;
  const int lr = t & 15, g = (t & 63) >> 4;
  const int srow = t >> 1;                 // staging row (2 lanes/row)
  const int kb0  = (t & 1)*2;              // staging k-blocks {0,1} or {2,3}
  const int ssw  = (srow >> 1) & 3;        // store swizzle for this row
  const int ks0  = ((kb0+0) ^ ssw)*8;
  const int ks1  = ((kb0+1) ^ ssw)*8;

  // two register staging sets (distance-2 pipeline)
  uint4 aAh0,aAh1,aAl0,aAl1,aBh0,aBh1,aBl0,aBl1;
  uint4 bAh0,bAh1,bAl0,bAl1,bBh0,bBh1,bBl0,bBl1;

#define LOADT(P, K0) { \
    const size_t go0 = (size_t)srow*K + (size_t)(K0) + (size_t)(kb0*8); \
    P##Ah0 = *(const uint4*)(Ahb + go0); P##Ah1 = *(const uint4*)(Ahb + go0 + 8); \
    P##Al0 = *(const uint4*)(Alb + go0); P##Al1 = *(const uint4*)(Alb + go0 + 8); \
    P##Bh0 = *(const uint4*)(Bhb + go0); P##Bh1 = *(const uint4*)(Bhb + go0 + 8); \
    P##Bl0 = *(const uint4*)(Blb + go0); P##Bl1 = *(const uint4*)(Blb + go0 + 8); }

#define WRITET(BUF, P) { \
    *(uint4*)&As_h##BUF[srow][ks0] = P##Ah0; *(uint4*)&As_h##BUF[srow][ks1] = P##Ah1; \
    *(uint4*)&As_l##BUF[srow][ks0] = P##Al0; *(uint4*)&As_l##BUF[srow][ks1] = P##Al1; \
    *(uint4*)&Bs_h##BUF[srow][ks0] = P##Bh0; *(uint4*)&Bs_h##BUF[srow][ks1] = P##Bh1; \
    *(uint4*)&Bs_l##BUF[srow][ks0] = P##Bl0; *(uint4*)&Bs_l##BUF[srow][ks1] = P##Bl1; }

#define COMPUTET(BUF) { \
    bf16x8 ah[4], al[4], bhf[4], blf[4]; \
    _Pragma("unroll") \
    for (int i=0;i<4;i++){ \
      const int ra = wm*64 + i*16 + lr; \
      const int ka = (g ^ ((ra>>1)&3))*8; \
      ah[i]  = *(const bf16x8*)&As_h##BUF[ra][ka]; \
      al[i]  = *(const bf16x8*)&As_l##BUF[ra][ka]; \
      const int rb = wn*64 + i*16 + lr; \
      const int kb = (g ^ ((rb>>1)&3))*8; \
      bhf[i] = *(const bf16x8*)&Bs_h##BUF[rb][kb]; \
      blf[i] = *(const bf16x8*)&Bs_l##BUF[rb][kb]; \
    } \
    _Pragma("unroll") \
    for (int mi=0;mi<4;mi++) \
      _Pragma("unroll") \
      for (int ni=0;ni<4;ni++){ \
        f32x4v c_ = acc[mi][ni]; \
        c_ = __builtin_amdgcn_mfma_f32_16x16x32_bf16(ah[mi], bhf[ni], c_, 0,0,0); \
        c_ = __builtin_amdgcn_mfma_f32_16x16x32_bf16(al[mi], bhf[ni], c_, 0,0,0); \
        c_ = __builtin_amdgcn_mfma_f32_16x16x32_bf16(ah[mi], blf[ni], c_, 0,0,0); \
        acc[mi][ni] = c_; \
      } }

  const int nk = K >> 5;                  // even for all call sites
  // prologue: buf0 <- tile0 ; regsA <- tile1 (in flight)
  LOADT(a, 0);
  WRITET(0, a);
  LOADT(a, 32);
  __syncthreads();

  // invariant entering iter t (even): buf0 = tile t, regsA = tile t+1 in flight
  for (int kt = 0; kt < nk; kt += 2){
    if (kt+2 < nk) LOADT(b, (kt+2)*32);   // issue early: consumed next half-iter
    COMPUTET(0);                          // tile kt
    WRITET(1, a);                         // tile kt+1 (vmcnt waits only on regsA)
    __syncthreads();
    if (kt+3 < nk) LOADT(a, (kt+3)*32);
    COMPUTET(1);                          // tile kt+1
    if (kt+2 < nk){ WRITET(0, b); }       // tile kt+2
    __syncthreads();
  }

#undef LOADT
#undef WRITET
#undef COMPUTET

  #pragma unroll
  for (int ni=0;ni<4;ni++){
    const int col = n0 + wn*64 + ni*16 + lr;
    const float bb = BIAS_ ? bias[col] : 0.f;
    #pragma unroll
    for (int mi=0;mi<4;mi++){
      const int r0 = m0 + wm*64 + mi*16 + g*4;
      #pragma unroll
      for (int r=0;r<4;r++){
        float v = acc[mi][ni][r] + bb;
        if (RES_) v += res[(size_t)(r0+r)*N + col];
        C[(size_t)(r0+r)*N + col] = v;
      }
    }
  }
}

// ---------------- LN(rep) + concat residual -> tx ----------------
__global__ __launch_bounds__(256) void ln_concat_kernel(const float* __restrict__ rep,
    const float* __restrict__ g, const float* __restrict__ b,
    const float* __restrict__ ch1, const float* __restrict__ ch2,
    float* __restrict__ tx){
  const int row = blockIdx.x;
  const float* x = rep + (size_t)row*D2;
  float s=0.f;
  for (int i=threadIdx.x;i<D2;i+=256) s += x[i];
  s = blockReduceSum256(s);
  const float mu = s / (float)D2;
  float v=0.f;
  for (int i=threadIdx.x;i<D2;i+=256){ float d = x[i]-mu; v += d*d; }
  v = blockReduceSum256(v);
  const float rs = rsqrtf(v/(float)D2 + 1e-5f);
  float* o = tx + (size_t)row*D2;
  for (int i=threadIdx.x;i<D2;i+=256){
    float val = (x[i]-mu)*rs*g[i] + b[i];
    float rv = (i<DD) ? ch1[(size_t)row*DD + i] : ch2[(size_t)row*DD + i - DD];
    o[i] = val + rv;
  }
}

// ---------------- depthwise 3x3 conv + bias + exact GELU (split bf16 out) --------
__global__ __launch_bounds__(256) void dwconv_gelu_kernel(const float* __restrict__ h1,
    const float* __restrict__ w, const float* __restrict__ bias,
    unsigned short* __restrict__ gh, unsigned short* __restrict__ gl){
  const int idx = blockIdx.x*256 + threadIdx.x;   // 16*32*384 = 196608 total
  const int b   = idx / 12288;                    // 12288 = 32*384 (uniform per block)
  const int r   = idx - b*12288;
  const int hh  = r / 384;
  const int c4  = r - hh*384;
  const int c   = c4*4;
  const float* base = h1 + (size_t)b*NN*C2 + c;
  const size_t obase = ((size_t)b*NN + hh*32)*C2 + c;

  f32x4v wk[9];
  #pragma unroll
  for (int k=0;k<9;k++){
    f32x4v t_;
    #pragma unroll
    for (int q=0;q<4;q++) t_[q] = w[(size_t)(c+q)*9 + k];
    wk[k] = t_;
  }
  f32x4v bvv;
  {
    const float4 bb = *(const float4*)(bias + c);
    bvv = (f32x4v){bb.x, bb.y, bb.z, bb.w};
  }

  const bool hm = (hh > 0), hp = (hh < 31);
  const f32x4v z4 = (f32x4v){0.f,0.f,0.f,0.f};
  const size_t rm = (size_t)((hh-1)*32)*C2;
  const size_t r0 = (size_t)( hh   *32)*C2;
  const size_t rp = (size_t)((hh+1)*32)*C2;

  f32x4v A0,A1,A2, B0,B1,B2, C0,C1,C2c;
  A0=z4; A1=z4; A2=z4;
  B0 = hm ? *(const f32x4v*)(base + rm) : z4;
  B1 =      *(const f32x4v*)(base + r0);
  B2 = hp ? *(const f32x4v*)(base + rp) : z4;
  C0 = hm ? *(const f32x4v*)(base + rm + C2) : z4;
  C1 =      *(const f32x4v*)(base + r0 + C2);
  C2c= hp ? *(const f32x4v*)(base + rp + C2) : z4;

  for (int ww=0; ww<32; ww++){
    f32x4v N0,N1,N2;
    if (ww < 30){
      const size_t co_ = (size_t)(ww+2)*C2;
      N0 = hm ? *(const f32x4v*)(base + rm + co_) : z4;
      N1 =      *(const f32x4v*)(base + r0 + co_) ;
      N2 = hp ? *(const f32x4v*)(base + rp + co_) : z4;
    } else { N0=z4; N1=z4; N2=z4; }

    f32x4v s = bvv;
    s += wk[0]*A0 + wk[1]*B0 + wk[2]*C0;
    s += wk[3]*A1 + wk[4]*B1 + wk[5]*C1;
    s += wk[6]*A2 + wk[7]*B2 + wk[8]*C2c;

    u16x4 hv, lv;
    #pragma unroll
    for (int q=0;q<4;q++){
      float rlt = 0.5f*s[q]*(1.f + erff(s[q]*0.70710678118654752f));
      unsigned short hhv = f2bf(rlt);
      hv[q] = hhv; lv[q] = f2bf(rlt - bf2f(hhv));
    }
    *(u16x4*)(gh + obase + (size_t)ww*C2) = hv;
    *(u16x4*)(gl + obase + (size_t)ww*C2) = lv;

    A0=B0; A1=B1; A2=B2;
    B0=C0; B1=C1; B2=C2c;
    C0=N0; C1=N1; C2c=N2;
  }
}

// ---------------- launch ----------------
extern "C" void kernel_launch(void* const* d_in, const int* in_sizes, int n_in,
                              void* d_out, int out_size, void* d_ws, size_t ws_size,
                              hipStream_t stream) {
  const float* x1     = (const float*)d_in[0];
  const float* x2     = (const float*)d_in[1];
  const float* ln1_g  = (const float*)d_in[2];
  const float* ln1_b  = (const float*)d_in[3];
  const float* qkv_w  = (const float*)d_in[4];
  const float* ca_temp= (const float*)d_in[5];
  const float* proj_w = (const float*)d_in[6];
  const float* proj_b = (const float*)d_in[7];
  const float* ln3_g  = (const float*)d_in[8];
  const float* ln3_b  = (const float*)d_in[9];
  const float* rp_w   = (const float*)d_in[10];
  const float* rp_b   = (const float*)d_in[11];
  const float* cn_g   = (const float*)d_in[12];
  const float* cn_b   = (const float*)d_in[13];
  const float* ln2_g  = (const float*)d_in[14];
  const float* ln2_b  = (const float*)d_in[15];
  const float* fc1_w  = (const float*)d_in[16];
  const float* fc1_b  = (const float*)d_in[17];
  const float* dw_w   = (const float*)d_in[18];
  const float* dw_b   = (const float*)d_in[19];
  const float* fc2_w  = (const float*)d_in[20];
  const float* fc2_b  = (const float*)d_in[21];
  float* out = (float*)d_out;
  float* W   = (float*)d_ws;

  // ---- workspace layout (peak 50,331,648 floats = 192 MiB) ----
  unsigned short* ycoh = (unsigned short*)W;        // SZ_ND u16
  unsigned short* ycol = ycoh + (size_t)SZ_ND;      // SZ_ND u16 (region = SZ_ND floats)
  unsigned short* coh  = ycoh;                      // reuse after qkv GEMM
  unsigned short* col  = ycol;
  float* qkvb = W + (size_t)SZ_ND;
  float* ch1  = W + 25165824ull;
  float* ch2  = W + 31457280ull;
  unsigned short* qkvwT_h  = (unsigned short*)(W + 37748736ull);
  unsigned short* qkvwT_l  = qkvwT_h + 442368u;
  unsigned short* projwT_h = qkvwT_l + 442368u;
  unsigned short* projwT_l = projwT_h + 147456u;
  float* n1  = W;
  float* n2  = W + (size_t)SZ_ND;
  float* KS  = W + 2ull*SZ_ND;
  float* QS  = W + 3ull*SZ_ND;
  float* ctx = W + (size_t)SZ_ND;
  float* ATb = W;
  unsigned short* ATbh = (unsigned short*)(W + 3ull*SZ_ND);
  unsigned short* ATbl = ATbh + (size_t)SZ_ND;
  float* rep = W + (size_t)SZ_ND;
  unsigned short* rpw_h = (unsigned short*)(W + 37748736ull);
  unsigned short* rpw_l = rpw_h + 294912u;
  float* txp  = out;
  float* h1   = W;
  unsigned short* y2h = (unsigned short*)(W + 25165824ull);
  unsigned short* y2l = y2h + (size_t)SZ_N2D;
  unsigned short* fc1wT_h = (unsigned short*)(W + 37748736ull);
  unsigned short* fc1wT_l = fc1wT_h + 1179648u;
  unsigned short* gh = (unsigned short*)(W + 25165824ull);
  unsigned short* gl = gh + (size_t)SZ_NC2;
  unsigned short* fc2wT_h = (unsigned short*)W;
  unsigned short* fc2wT_l = fc2wT_h + 1179648u;

  const int M = BN*NN;

  // ---- phase-A weight prep ----
  wconv_t_kernel<<<dim3(1152/32, DD/32), dim3(256), 0, stream>>>(qkv_w, qkvwT_h, qkvwT_l, DD, 1152);
  wconv_t_kernel<<<dim3(DD/32, DD/32), dim3(256), 0, stream>>>(proj_w, projwT_h, projwT_l, DD, DD);

  // ---- channel attention, stream 1 ----
  ln_split_kernel<<<dim3(M), dim3(256), 0, stream>>>(x1, ln1_g, ln1_b, ycoh, ycol, DD);
  gemm_bf16x3s_kernel<false,false><<<dim3(1152/128, M/128), dim3(256), 0, stream>>>(
      ycoh, ycol, qkvwT_h, qkvwT_l, nullptr, nullptr, qkvb, M, 1152, DD);
  chattn_mfma_kernel<<<dim3(BN*NHEAD), dim3(256), 0, stream>>>(qkvb, ca_temp, coh, col);
  gemm_bf16x3s_kernel<true,true><<<dim3(DD/128, M/128), dim3(256), 0, stream>>>(
      coh, col, projwT_h, projwT_l, proj_b, x1, ch1, M, DD, DD);

  // ---- channel attention, stream 2 ----
  ln_split_kernel<<<dim3(M), dim3(256), 0, stream>>>(x2, ln1_g, ln1_b, ycoh, ycol, DD);
  gemm_bf16x3s_kernel<false,false><<<dim3(1152/128, M/128), dim3(256), 0, stream>>>(
      ycoh, ycol, qkvwT_h, qkvwT_l, nullptr, nullptr, qkvb, M, 1152, DD);
  chattn_mfma_kernel<<<dim3(BN*NHEAD), dim3(256), 0, stream>>>(qkvb, ca_temp, coh, col);
  gemm_bf16x3s_kernel<true,true><<<dim3(DD/128, M/128), dim3(256), 0, stream>>>(
      coh, col, projwT_h, projwT_l, proj_b, x2, ch2, M, DD, DD);

  // ---- cross attention ----
  wconv_kernel<<<dim3(294912/256), dim3(256), 0, stream>>>(rp_w, rpw_h, rpw_l, 294912);
  ln_kernel<<<dim3(M), dim3(256), 0, stream>>>(ch1, ln3_g, ln3_b, n1, DD);
  ln_kernel<<<dim3(M), dim3(256), 0, stream>>>(ch2, ln3_g, ln3_b, n2, DD);
  rowsoftmax_kernel<<<dim3(M), dim3(256), 0, stream>>>(n2, QS, DD);
  colsoftmax_kernel<<<dim3(DD/64, BN), dim3(256), 0, stream>>>(n2, KS);
  gemm64_kernel<true,false,false,false><<<dim3(DD/64, DD/64, BN), dim3(256), 0, stream>>>(
      KS, n1, nullptr, nullptr, ctx, DD, DD, NN,
      (size_t)NN*DD, (size_t)NN*DD, (size_t)DD*DD);
  gemm64_kernel<false,false,false,false><<<dim3(DD/64, NN/64, BN), dim3(256), 0, stream>>>(
      QS, ctx, nullptr, nullptr, ATb, NN, DD, DD,
      (size_t)NN*DD, (size_t)DD*DD, (size_t)NN*DD);
  wconv_kernel<<<dim3(SZ_ND/256), dim3(256), 0, stream>>>(ATb, ATbh, ATbl, SZ_ND);
  gemm_bf16x3s_kernel<true,false><<<dim3(D2/128, M/128), dim3(256), 0, stream>>>(
      ATbh, ATbl, rpw_h, rpw_l, rp_b, nullptr, rep, M, D2, DD);
  ln_concat_kernel<<<dim3(M), dim3(256), 0, stream>>>(rep, cn_g, cn_b, ch1, ch2, txp);

  // ---- mix FFN ----
  wconv_t_kernel<<<dim3(C2/32, D2/32), dim3(256), 0, stream>>>(fc1_w, fc1wT_h, fc1wT_l, D2, C2);
  ln_split_kernel<<<dim3(M), dim3(256), 0, stream>>>(txp, ln2_g, ln2_b, y2h, y2l, D2);
  gemm_bf16x3s_kernel<true,false><<<dim3(C2/128, M/128), dim3(256), 0, stream>>>(
      y2h, y2l, fc1wT_h, fc1wT_l, fc1_b, nullptr, h1, M, C2, D2);
  dwconv_gelu_kernel<<<dim3(196608/256), dim3(256), 0, stream>>>(h1, dw_w, dw_b, gh, gl);
  wconv_t_kernel<<<dim3(D2/32, C2/32), dim3(256), 0, stream>>>(fc2_w, fc2wT_h, fc2wT_l, C2, D2);
  gemm_bf16x3s_kernel<true,true><<<dim3(D2/128, M/128), dim3(256), 0, stream>>>(
      gh, gl, fc2wT_h, fc2wT_l, fc2_b, txp, out, M, D2, C2);
}

// Round 7
// 965.457 us; speedup vs baseline: 1.3195x; 1.1055x over previous
//
#include <hip/hip_runtime.h>
#include <math.h>

#define BN 16
#define NN 1024
#define DD 384
#define D2 768
#define C2 1536
#define NHEAD 8
#define DH 48

#define SZ_ND   (BN*NN*DD)      /* 6291456  */
#define SZ_N2D  (BN*NN*D2)      /* 12582912 */
#define SZ_NC2  (BN*NN*C2)      /* 25165824 */

typedef __bf16 bf16x8 __attribute__((ext_vector_type(8)));
typedef float f32x4v __attribute__((ext_vector_type(4)));
typedef unsigned short u16x4 __attribute__((ext_vector_type(4)));

__device__ __forceinline__ unsigned short f2bf(float x){
  unsigned int u = __float_as_uint(x);
  u += 0x7FFFu + ((u >> 16) & 1u);          // round-nearest-even to bf16
  return (unsigned short)(u >> 16);
}
__device__ __forceinline__ float bf2f(unsigned short h){
  return __uint_as_float(((unsigned int)h) << 16);
}

// ---------------- block reductions (256 threads = 4 waves) ----------------
__device__ __forceinline__ float blockReduceSum256(float v){
  __shared__ float red[4];
  #pragma unroll
  for (int o=32;o;o>>=1) v += __shfl_down(v,o,64);
  if ((threadIdx.x&63)==0) red[threadIdx.x>>6]=v;
  __syncthreads();
  float r = red[0]+red[1]+red[2]+red[3];
  __syncthreads();
  return r;
}
__device__ __forceinline__ float blockReduceMax256(float v){
  __shared__ float red[4];
  #pragma unroll
  for (int o=32;o;o>>=1) v = fmaxf(v, __shfl_down(v,o,64));
  if ((threadIdx.x&63)==0) red[threadIdx.x>>6]=v;
  __syncthreads();
  float r = fmaxf(fmaxf(red[0],red[1]),fmaxf(red[2],red[3]));
  __syncthreads();
  return r;
}

// ---------------- LayerNorm: one block per row (fp32 out) ----------------
__global__ __launch_bounds__(256) void ln_kernel(const float* __restrict__ in,
    const float* __restrict__ g, const float* __restrict__ b,
    float* __restrict__ out, int C){
  const int row = blockIdx.x;
  const float* x = in + (size_t)row*C;
  float s=0.f;
  for (int i=threadIdx.x;i<C;i+=256) s += x[i];
  s = blockReduceSum256(s);
  const float mu = s / (float)C;
  float v=0.f;
  for (int i=threadIdx.x;i<C;i+=256){ float d = x[i]-mu; v += d*d; }
  v = blockReduceSum256(v);
  const float rs = rsqrtf(v/(float)C + 1e-5f);
  float* o = out + (size_t)row*C;
  for (int i=threadIdx.x;i<C;i+=256) o[i] = (x[i]-mu)*rs*g[i] + b[i];
}

// ---------------- LayerNorm with bf16 hi/lo split output ----------------
__global__ __launch_bounds__(256) void ln_split_kernel(const float* __restrict__ in,
    const float* __restrict__ g, const float* __restrict__ b,
    unsigned short* __restrict__ oh, unsigned short* __restrict__ ol, int C){
  const int row = blockIdx.x;
  const float* x = in + (size_t)row*C;
  float s=0.f;
  for (int i=threadIdx.x;i<C;i+=256) s += x[i];
  s = blockReduceSum256(s);
  const float mu = s / (float)C;
  float v=0.f;
  for (int i=threadIdx.x;i<C;i+=256){ float d = x[i]-mu; v += d*d; }
  v = blockReduceSum256(v);
  const float rs = rsqrtf(v/(float)C + 1e-5f);
  unsigned short* ohp = oh + (size_t)row*C;
  unsigned short* olp = ol + (size_t)row*C;
  for (int i=threadIdx.x;i<C;i+=256){
    float val = (x[i]-mu)*rs*g[i] + b[i];
    unsigned short hh = f2bf(val);
    ohp[i] = hh; olp[i] = f2bf(val - bf2f(hh));
  }
}

// ---------------- row softmax with bf16 hi/lo split output (QS) ----------------
__global__ __launch_bounds__(256) void rowsoftmax_split_kernel(const float* __restrict__ in,
    unsigned short* __restrict__ oh, unsigned short* __restrict__ ol, int C){
  const int row = blockIdx.x;
  const float* x = in + (size_t)row*C;
  float m = -3.0e38f;
  for (int i=threadIdx.x;i<C;i+=256) m = fmaxf(m, x[i]);
  m = blockReduceMax256(m);
  float s = 0.f;
  for (int i=threadIdx.x;i<C;i+=256) s += expf(x[i]-m);
  s = blockReduceSum256(s);
  const float inv = 1.f/s;
  unsigned short* ohp = oh + (size_t)row*C;
  unsigned short* olp = ol + (size_t)row*C;
  for (int i=threadIdx.x;i<C;i+=256){
    float p = expf(x[i]-m)*inv;
    unsigned short hh = f2bf(p);
    ohp[i] = hh; olp[i] = f2bf(p - bf2f(hh));
  }
}

// ---------------- column softmax over tokens n (KS, fp32 out) ----------------
__global__ __launch_bounds__(256) void colsoftmax_kernel(const float* __restrict__ in,
    float* __restrict__ out){
  const int dl = threadIdx.x & 63;
  const int nc = threadIdx.x >> 6;
  const int d  = blockIdx.x*64 + dl;
  const int b  = blockIdx.y;
  const float* p = in + (size_t)b*NN*DD + d;
  __shared__ float redm[4][64];
  __shared__ float reds[4][64];
  float m = -3.0e38f;
  for (int n=nc*256; n<nc*256+256; n++) m = fmaxf(m, p[(size_t)n*DD]);
  redm[nc][dl] = m; __syncthreads();
  m = fmaxf(fmaxf(redm[0][dl],redm[1][dl]),fmaxf(redm[2][dl],redm[3][dl]));
  float s=0.f;
  for (int n=nc*256;n<nc*256+256;n++) s += expf(p[(size_t)n*DD]-m);
  reds[nc][dl]=s; __syncthreads();
  s = reds[0][dl]+reds[1][dl]+reds[2][dl]+reds[3][dl];
  const float inv = 1.f/s;
  float* q = out + (size_t)b*NN*DD + d;
  for (int n=nc*256;n<nc*256+256;n++) q[(size_t)n*DD] = expf(p[(size_t)n*DD]-m)*inv;
}

// ---------------- batched transpose + split: fp32 [z][R][C] -> u16 hi/lo [z][C][R] ---
__global__ __launch_bounds__(256) void tsplit_kernel(const float* __restrict__ in,
    unsigned short* __restrict__ oh, unsigned short* __restrict__ ol, int R, int Cc){
  const size_t zb = (size_t)blockIdx.z * R * Cc;
  const float* ip = in + zb;
  unsigned short* ohp = oh + zb;
  unsigned short* olp = ol + zb;
  __shared__ float tile[32][33];
  const int c0 = blockIdx.x*32, r0 = blockIdx.y*32;
  const int j = threadIdx.x & 31, i4 = threadIdx.x >> 5;
  #pragma unroll
  for (int s=0;s<4;s++){
    int i = i4*4+s;
    tile[i][j] = ip[(size_t)(r0+i)*Cc + c0 + j];
  }
  __syncthreads();
  #pragma unroll
  for (int s=0;s<4;s++){
    int i = i4*4+s;
    float x = tile[j][i];                       // in[r0+j][c0+i]
    unsigned short h = f2bf(x);
    ohp[(size_t)(c0+i)*R + r0 + j] = h;
    olp[(size_t)(c0+i)*R + r0 + j] = f2bf(x - bf2f(h));
  }
}

// ---------------- channel attention, MFMA version (split bf16 output) ------------
__global__ __launch_bounds__(256) void chattn_mfma_kernel(
    const float* __restrict__ qkv, const float* __restrict__ temp,
    unsigned short* __restrict__ coh, unsigned short* __restrict__ col)
{
  const int bh = blockIdx.x, b = bh >> 3, h = bh & 7;
  const int t = threadIdx.x, w = t >> 6, lane = t & 63;
  const int lr = lane & 15, g = lane >> 4;

  __shared__ __align__(16) unsigned char ldsA[27648];
  unsigned short (*Qh)[72] = (unsigned short(*)[72])(ldsA);
  unsigned short (*Ql)[72] = (unsigned short(*)[72])(ldsA + 6912);
  unsigned short (*Kh)[72] = (unsigned short(*)[72])(ldsA + 13824);
  unsigned short (*Kl)[72] = (unsigned short(*)[72])(ldsA + 20736);
  unsigned short (*Vh)[72] = (unsigned short(*)[72])(ldsA);
  unsigned short (*Vl)[72] = (unsigned short(*)[72])(ldsA + 9216);
  __shared__ unsigned short Ph[48][72], Pl[48][72];
  __shared__ float S[48][49];
  __shared__ float qn[48], kn[48];

  const size_t base = (size_t)b*NN*1152 + (size_t)h*48;

  int agrp[3], apr[3], aoff[3];
  #pragma unroll
  for (int l=0;l<3;l++){
    int idx = l*256+t;
    int mo = (idx>=384) ? 1 : 0;
    int a = idx - mo*384;
    agrp[l] = a%12; apr[l] = a/12; aoff[l] = mo*384;
  }

  f32x4v acc[12];
  #pragma unroll
  for (int i=0;i<12;i++) acc[i] = (f32x4v){0.f,0.f,0.f,0.f};

  float4 cur[3][2];
  #pragma unroll
  for (int l=0;l<3;l++){
    const float* p = qkv + base + (size_t)(apr[l]*2)*1152 + aoff[l] + agrp[l]*4;
    cur[l][0] = *(const float4*)p;
    cur[l][1] = *(const float4*)(p+1152);
  }

  for (int nc=0; nc<16; nc++){
    #pragma unroll
    for (int l=0;l<3;l++){
      unsigned short (*Dh)[72] = aoff[l] ? Kh : Qh;
      unsigned short (*Dl)[72] = aoff[l] ? Kl : Ql;
      const float x0[4] = {cur[l][0].x, cur[l][0].y, cur[l][0].z, cur[l][0].w};
      const float x1[4] = {cur[l][1].x, cur[l][1].y, cur[l][1].z, cur[l][1].w};
      #pragma unroll
      for (int c=0;c<4;c++){
        int d = agrp[l]*4+c;
        unsigned short h0 = f2bf(x0[c]), h1 = f2bf(x1[c]);
        unsigned short l0 = f2bf(x0[c]-bf2f(h0)), l1 = f2bf(x1[c]-bf2f(h1));
        *(unsigned int*)&Dh[d][apr[l]*2] = (unsigned)h0 | ((unsigned)h1<<16);
        *(unsigned int*)&Dl[d][apr[l]*2] = (unsigned)l0 | ((unsigned)l1<<16);
      }
    }
    __syncthreads();
    if (nc < 15){
      #pragma unroll
      for (int l=0;l<3;l++){
        const float* p = qkv + base + (size_t)((nc+1)*64 + apr[l]*2)*1152 + aoff[l] + agrp[l]*4;
        cur[l][0] = *(const float4*)p;
        cur[l][1] = *(const float4*)(p+1152);
      }
    }
    if (w < 3){
      #pragma unroll
      for (int ks=0;ks<2;ks++){
        bf16x8 a_h = *(const bf16x8*)&Qh[w*16+lr][ks*32+g*8];
        bf16x8 a_l = *(const bf16x8*)&Ql[w*16+lr][ks*32+g*8];
        #pragma unroll
        for (int c=0;c<3;c++){
          bf16x8 b_h = *(const bf16x8*)&Kh[c*16+lr][ks*32+g*8];
          bf16x8 b_l = *(const bf16x8*)&Kl[c*16+lr][ks*32+g*8];
          acc[c] = __builtin_amdgcn_mfma_f32_16x16x32_bf16(a_h, b_h, acc[c], 0,0,0);
          acc[c] = __builtin_amdgcn_mfma_f32_16x16x32_bf16(a_l, b_h, acc[c], 0,0,0);
          acc[c] = __builtin_amdgcn_mfma_f32_16x16x32_bf16(a_h, b_l, acc[c], 0,0,0);
        }
      }
    } else {
      #pragma unroll
      for (int ks=0;ks<2;ks++){
        #pragma unroll
        for (int c=0;c<3;c++){
          bf16x8 qh_ = *(const bf16x8*)&Qh[c*16+lr][ks*32+g*8];
          bf16x8 ql_ = *(const bf16x8*)&Ql[c*16+lr][ks*32+g*8];
          bf16x8 kh_ = *(const bf16x8*)&Kh[c*16+lr][ks*32+g*8];
          bf16x8 kl_ = *(const bf16x8*)&Kl[c*16+lr][ks*32+g*8];
          acc[c]   = __builtin_amdgcn_mfma_f32_16x16x32_bf16(qh_, qh_, acc[c],   0,0,0);
          acc[3+c] = __builtin_amdgcn_mfma_f32_16x16x32_bf16(qh_, ql_, acc[3+c], 0,0,0);
          acc[6+c] = __builtin_amdgcn_mfma_f32_16x16x32_bf16(kh_, kh_, acc[6+c], 0,0,0);
          acc[9+c] = __builtin_amdgcn_mfma_f32_16x16x32_bf16(kh_, kl_, acc[9+c], 0,0,0);
        }
      }
    }
    __syncthreads();
  }

  const float tp = temp[h];
  if (w == 3){
    if ((lane>>4) == ((lane&15)>>2)){
      int p = lane & 15, r = p & 3;
      #pragma unroll
      for (int c=0;c<3;c++){
        float q2 = fmaxf(acc[c][r]   + 2.f*acc[3+c][r], 0.f);
        float k2 = fmaxf(acc[6+c][r] + 2.f*acc[9+c][r], 0.f);
        qn[c*16+p] = fmaxf(sqrtf(q2), 1e-12f);
        kn[c*16+p] = fmaxf(sqrtf(k2), 1e-12f);
      }
    }
  }
  __syncthreads();
  if (w < 3){
    #pragma unroll
    for (int c=0;c<3;c++){
      #pragma unroll
      for (int r=0;r<4;r++){
        int i = w*16 + g*4 + r, j = c*16 + lr;
        S[i][j] = acc[c][r]*tp/(qn[i]*kn[j]);
      }
    }
  }
  __syncthreads();

  int vgrp[3], vtk[3];
  #pragma unroll
  for (int l=0;l<3;l++){ int idx=l*256+t; vtk[l]=idx/12; vgrp[l]=idx%12; }
  float4 pv[3];
  #pragma unroll
  for (int l=0;l<3;l++)
    pv[l] = *(const float4*)(qkv + base + (size_t)vtk[l]*1152 + 768 + vgrp[l]*4);

  if (t < 48){
    float m = -3.0e38f;
    for (int j=0;j<48;j++) m = fmaxf(m, S[t][j]);
    float s = 0.f;
    for (int j=0;j<48;j++){ float e_ = expf(S[t][j]-m); S[t][j] = e_; s += e_; }
    float inv = 1.f/s;
    for (int j=0;j<48;j++){
      float p = S[t][j]*inv;
      unsigned short hp = f2bf(p);
      Ph[t][j] = hp; Pl[t][j] = f2bf(p - bf2f(hp));
    }
    #pragma unroll
    for (int j=48;j<64;j++){ Ph[t][j]=0; Pl[t][j]=0; }
  } else {
    const u16x4 z4 = (u16x4){0,0,0,0};
    for (int idx=t-48; idx<512; idx+=208){
      int tk = idx>>3, q = idx&7;
      if (q<4) *(u16x4*)&Vh[tk][48+(q&3)*4] = z4;
      else     *(u16x4*)&Vl[tk][48+(q&3)*4] = z4;
    }
  }
  __syncthreads();

  bf16x8 pfh[3][2], pfl[3][2];
  #pragma unroll
  for (int it=0;it<3;it++)
    #pragma unroll
    for (int ks=0;ks<2;ks++){
      pfh[it][ks] = *(const bf16x8*)&Ph[it*16+lr][ks*32+g*8];
      pfl[it][ks] = *(const bf16x8*)&Pl[it*16+lr][ks*32+g*8];
    }

  for (int vc=0; vc<16; vc++){
    #pragma unroll
    for (int l=0;l<3;l++){
      const float xv[4] = {pv[l].x, pv[l].y, pv[l].z, pv[l].w};
      u16x4 hv, lv;
      #pragma unroll
      for (int c=0;c<4;c++){
        unsigned short hh = f2bf(xv[c]);
        hv[c] = hh; lv[c] = f2bf(xv[c] - bf2f(hh));
      }
      *(u16x4*)&Vh[vtk[l]][vgrp[l]*4] = hv;
      *(u16x4*)&Vl[vtk[l]][vgrp[l]*4] = lv;
    }
    __syncthreads();
    if (vc < 15){
      #pragma unroll
      for (int l=0;l<3;l++)
        pv[l] = *(const float4*)(qkv + base + (size_t)((vc+1)*64+vtk[l])*1152 + 768 + vgrp[l]*4);
    }
    bf16x8 vfh[2], vfl[2];
    #pragma unroll
    for (int ks=0;ks<2;ks++){
      vfh[ks] = *(const bf16x8*)&Vh[w*16+lr][ks*32+g*8];
      vfl[ks] = *(const bf16x8*)&Vl[w*16+lr][ks*32+g*8];
    }
    f32x4v o[3];
    #pragma unroll
    for (int it=0;it<3;it++) o[it] = (f32x4v){0.f,0.f,0.f,0.f};
    #pragma unroll
    for (int it=0;it<3;it++)
      #pragma unroll
      for (int ks=0;ks<2;ks++){
        o[it] = __builtin_amdgcn_mfma_f32_16x16x32_bf16(pfh[it][ks], vfh[ks], o[it], 0,0,0);
        o[it] = __builtin_amdgcn_mfma_f32_16x16x32_bf16(pfl[it][ks], vfh[ks], o[it], 0,0,0);
        o[it] = __builtin_amdgcn_mfma_f32_16x16x32_bf16(pfh[it][ks], vfl[ks], o[it], 0,0,0);
      }
    const int n = vc*64 + w*16 + lr;
    #pragma unroll
    for (int it=0;it<3;it++){
      const size_t off = ((size_t)b*NN + n)*DD + h*48 + it*16 + g*4;
      u16x4 hv, lv;
      #pragma unroll
      for (int r=0;r<4;r++){
        float x = o[it][r];
        unsigned short hh = f2bf(x);
        hv[r] = hh; lv[r] = f2bf(x - bf2f(hh));
      }
      *(u16x4*)(coh + off) = hv;
      *(u16x4*)(col + off) = lv;
    }
    __syncthreads();
  }
}

// ---------------- weight prep: transpose [K,N] -> bf16 hi/lo [N][K] ----------------
__global__ __launch_bounds__(256) void wconv_t_kernel(const float* __restrict__ in,
    unsigned short* __restrict__ oh, unsigned short* __restrict__ ol, int K, int N){
  __shared__ float tile[32][33];
  const int n0 = blockIdx.x*32, k0 = blockIdx.y*32;
  const int j = threadIdx.x & 31, i4 = threadIdx.x >> 5;
  #pragma unroll
  for (int s=0;s<4;s++){
    int i = i4*4+s;
    tile[i][j] = in[(size_t)(k0+i)*N + n0 + j];
  }
  __syncthreads();
  #pragma unroll
  for (int s=0;s<4;s++){
    int i = i4*4+s;
    float x = tile[j][i];                       // in[k0+j][n0+i]
    unsigned short h = f2bf(x);
    oh[(size_t)(n0+i)*K + k0 + j] = h;
    ol[(size_t)(n0+i)*K + k0 + j] = f2bf(x - bf2f(h));
  }
}

// ---------------- elementwise split fp32 -> bf16 hi/lo ----------------
__global__ __launch_bounds__(256) void wconv_kernel(const float* __restrict__ in,
    unsigned short* __restrict__ oh, unsigned short* __restrict__ ol, int n){
  int i = blockIdx.x*256 + threadIdx.x;
  if (i < n){
    float x = in[i];
    unsigned short h = f2bf(x);
    oh[i] = h;
    ol[i] = f2bf(x - bf2f(h));
  }
}

// ---------------- bf16x3 MFMA GEMM: dbuf LDS + distance-2 prefetch, batched -------
// C[M,N] = A (bf16 hi/lo [M][K]) * B (bf16 hi/lo [N][K]) (+bias)(+res)
// 128x128 tile, BK=32, 4 waves, LDS dbuf + 16B-block swizzle (R5: 0 conflicts).
// SPLIT_: write C as bf16 hi/lo planes (no bias/res). Batched via blockIdx.z.
// XCD swizzle only when nwg%8==0 (bijectivity guard, ERRATA #11).
template<bool BIAS_, bool RES_, bool SPLIT_>
__global__ __launch_bounds__(256) void gemm_bf16x3s_kernel(
    const unsigned short* __restrict__ Ah, const unsigned short* __restrict__ Al,
    const unsigned short* __restrict__ Bh, const unsigned short* __restrict__ Bl,
    const float* __restrict__ bias, const float* __restrict__ res,
    float* __restrict__ C, unsigned short* __restrict__ Ch, unsigned short* __restrict__ Cl,
    int M, int N, int K, size_t sAz, size_t sBz, size_t sCz)
{
  const int t = threadIdx.x;
  const int nwg = gridDim.x*gridDim.y;
  const int lin = blockIdx.y*gridDim.x + blockIdx.x;
  const int swz = ((nwg & 7)==0) ? ((lin & 7)*(nwg >> 3) + (lin >> 3)) : lin;
  const int bx = swz % gridDim.x, by = swz / gridDim.x;
  const int m0 = by*128, n0 = bx*128;
  const size_t zo = (size_t)blockIdx.z;

  __shared__ unsigned short As_h0[128][32], As_l0[128][32];
  __shared__ unsigned short Bs_h0[128][32], Bs_l0[128][32];
  __shared__ unsigned short As_h1[128][32], As_l1[128][32];
  __shared__ unsigned short Bs_h1[128][32], Bs_l1[128][32];

  const unsigned short* Ahb = Ah + zo*sAz + (size_t)m0*K;
  const unsigned short* Alb = Al + zo*sAz + (size_t)m0*K;
  const unsigned short* Bhb = Bh + zo*sBz + (size_t)n0*K;
  const unsigned short* Blb = Bl + zo*sBz + (size_t)n0*K;

  f32x4v acc[4][4];
  #pragma unroll
  for (int i=0;i<4;i++)
    #pragma unroll
    for (int j=0;j<4;j++) acc[i][j] = (f32x4v){0.f,0.f,0.f,0.f};

  const int w  = t >> 6;
  const int wm = w >> 1, wn = w & 1;
  const int lr = t & 15, g = (t & 63) >> 4;
  const int srow = t >> 1;                 // staging row (2 lanes/row)
  const int kb0  = (t & 1)*2;              // staging k-blocks {0,1} or {2,3}
  const int ssw  = (srow >> 1) & 3;        // store swizzle for this row
  const int ks0  = ((kb0+0) ^ ssw)*8;
  const int ks1  = ((kb0+1) ^ ssw)*8;

  uint4 aAh0,aAh1,aAl0,aAl1,aBh0,aBh1,aBl0,aBl1;
  uint4 bAh0,bAh1,bAl0,bAl1,bBh0,bBh1,bBl0,bBl1;

#define LOADT(P, K0) { \
    const size_t go0 = (size_t)srow*K + (size_t)(K0) + (size_t)(kb0*8); \
    P##Ah0 = *(const uint4*)(Ahb + go0); P##Ah1 = *(const uint4*)(Ahb + go0 + 8); \
    P##Al0 = *(const uint4*)(Alb + go0); P##Al1 = *(const uint4*)(Alb + go0 + 8); \
    P##Bh0 = *(const uint4*)(Bhb + go0); P##Bh1 = *(const uint4*)(Bhb + go0 + 8); \
    P##Bl0 = *(const uint4*)(Blb + go0); P##Bl1 = *(const uint4*)(Blb + go0 + 8); }

#define WRITET(BUF, P) { \
    *(uint4*)&As_h##BUF[srow][ks0] = P##Ah0; *(uint4*)&As_h##BUF[srow][ks1] = P##Ah1; \
    *(uint4*)&As_l##BUF[srow][ks0] = P##Al0; *(uint4*)&As_l##BUF[srow][ks1] = P##Al1; \
    *(uint4*)&Bs_h##BUF[srow][ks0] = P##Bh0; *(uint4*)&Bs_h##BUF[srow][ks1] = P##Bh1; \
    *(uint4*)&Bs_l##BUF[srow][ks0] = P##Bl0; *(uint4*)&Bs_l##BUF[srow][ks1] = P##Bl1; }

#define COMPUTET(BUF) { \
    bf16x8 ah[4], al[4], bhf[4], blf[4]; \
    _Pragma("unroll") \
    for (int i=0;i<4;i++){ \
      const int ra = wm*64 + i*16 + lr; \
      const int ka = (g ^ ((ra>>1)&3))*8; \
      ah[i]  = *(const bf16x8*)&As_h##BUF[ra][ka]; \
      al[i]  = *(const bf16x8*)&As_l##BUF[ra][ka]; \
      const int rb = wn*64 + i*16 + lr; \
      const int kb = (g ^ ((rb>>1)&3))*8; \
      bhf[i] = *(const bf16x8*)&Bs_h##BUF[rb][kb]; \
      blf[i] = *(const bf16x8*)&Bs_l##BUF[rb][kb]; \
    } \
    _Pragma("unroll") \
    for (int mi=0;mi<4;mi++) \
      _Pragma("unroll") \
      for (int ni=0;ni<4;ni++){ \
        f32x4v c_ = acc[mi][ni]; \
        c_ = __builtin_amdgcn_mfma_f32_16x16x32_bf16(ah[mi], bhf[ni], c_, 0,0,0); \
        c_ = __builtin_amdgcn_mfma_f32_16x16x32_bf16(al[mi], bhf[ni], c_, 0,0,0); \
        c_ = __builtin_amdgcn_mfma_f32_16x16x32_bf16(ah[mi], blf[ni], c_, 0,0,0); \
        acc[mi][ni] = c_; \
      } }

  const int nk = K >> 5;                  // even for all call sites
  LOADT(a, 0);
  WRITET(0, a);
  LOADT(a, 32);
  __syncthreads();

  for (int kt = 0; kt < nk; kt += 2){
    if (kt+2 < nk) LOADT(b, (kt+2)*32);
    COMPUTET(0);
    WRITET(1, a);
    __syncthreads();
    if (kt+3 < nk) LOADT(a, (kt+3)*32);
    COMPUTET(1);
    if (kt+2 < nk){ WRITET(0, b); }
    __syncthreads();
  }

#undef LOADT
#undef WRITET
#undef COMPUTET

  if (SPLIT_){
    unsigned short* Chb = Ch + zo*sCz;
    unsigned short* Clb = Cl + zo*sCz;
    #pragma unroll
    for (int ni=0;ni<4;ni++){
      const int col = n0 + wn*64 + ni*16 + lr;
      #pragma unroll
      for (int mi=0;mi<4;mi++){
        const int r0 = m0 + wm*64 + mi*16 + g*4;
        #pragma unroll
        for (int r=0;r<4;r++){
          float v = acc[mi][ni][r];
          unsigned short hv = f2bf(v);
          const size_t off = (size_t)(r0+r)*N + col;
          Chb[off] = hv;
          Clb[off] = f2bf(v - bf2f(hv));
        }
      }
    }
  } else {
    float* Cb = C + zo*sCz;
    const float* resb = RES_ ? (res + zo*sCz) : nullptr;
    #pragma unroll
    for (int ni=0;ni<4;ni++){
      const int col = n0 + wn*64 + ni*16 + lr;
      const float bb = BIAS_ ? bias[col] : 0.f;
      #pragma unroll
      for (int mi=0;mi<4;mi++){
        const int r0 = m0 + wm*64 + mi*16 + g*4;
        #pragma unroll
        for (int r=0;r<4;r++){
          float v = acc[mi][ni][r] + bb;
          if (RES_) v += resb[(size_t)(r0+r)*N + col];
          Cb[(size_t)(r0+r)*N + col] = v;
        }
      }
    }
  }
}

// ---------------- LN(rep) + concat residual -> tx ----------------
__global__ __launch_bounds__(256) void ln_concat_kernel(const float* __restrict__ rep,
    const float* __restrict__ g, const float* __restrict__ b,
    const float* __restrict__ ch1, const float* __restrict__ ch2,
    float* __restrict__ tx){
  const int row = blockIdx.x;
  const float* x = rep + (size_t)row*D2;
  float s=0.f;
  for (int i=threadIdx.x;i<D2;i+=256) s += x[i];
  s = blockReduceSum256(s);
  const float mu = s / (float)D2;
  float v=0.f;
  for (int i=threadIdx.x;i<D2;i+=256){ float d = x[i]-mu; v += d*d; }
  v = blockReduceSum256(v);
  const float rs = rsqrtf(v/(float)D2 + 1e-5f);
  float* o = tx + (size_t)row*D2;
  for (int i=threadIdx.x;i<D2;i+=256){
    float val = (x[i]-mu)*rs*g[i] + b[i];
    float rv = (i<DD) ? ch1[(size_t)row*DD + i] : ch2[(size_t)row*DD + i - DD];
    o[i] = val + rv;
  }
}

// ---------------- depthwise 3x3 conv + bias + exact GELU (split bf16 out) --------
__global__ __launch_bounds__(256) void dwconv_gelu_kernel(const float* __restrict__ h1,
    const float* __restrict__ w, const float* __restrict__ bias,
    unsigned short* __restrict__ gh, unsigned short* __restrict__ gl){
  const int idx = blockIdx.x*256 + threadIdx.x;
  const int b   = idx / 12288;
  const int r   = idx - b*12288;
  const int hh  = r / 384;
  const int c4  = r - hh*384;
  const int c   = c4*4;
  const float* base = h1 + (size_t)b*NN*C2 + c;
  const size_t obase = ((size_t)b*NN + hh*32)*C2 + c;

  f32x4v wk[9];
  #pragma unroll
  for (int k=0;k<9;k++){
    f32x4v t_;
    #pragma unroll
    for (int q=0;q<4;q++) t_[q] = w[(size_t)(c+q)*9 + k];
    wk[k] = t_;
  }
  f32x4v bvv;
  {
    const float4 bb = *(const float4*)(bias + c);
    bvv = (f32x4v){bb.x, bb.y, bb.z, bb.w};
  }

  const bool hm = (hh > 0), hp = (hh < 31);
  const f32x4v z4 = (f32x4v){0.f,0.f,0.f,0.f};
  const size_t rm = (size_t)((hh-1)*32)*C2;
  const size_t r0 = (size_t)( hh   *32)*C2;
  const size_t rp = (size_t)((hh+1)*32)*C2;

  f32x4v A0,A1,A2, B0,B1,B2, C0,C1,C2c;
  A0=z4; A1=z4; A2=z4;
  B0 = hm ? *(const f32x4v*)(base + rm) : z4;
  B1 =      *(const f32x4v*)(base + r0);
  B2 = hp ? *(const f32x4v*)(base + rp) : z4;
  C0 = hm ? *(const f32x4v*)(base + rm + C2) : z4;
  C1 =      *(const f32x4v*)(base + r0 + C2);
  C2c= hp ? *(const f32x4v*)(base + rp + C2) : z4;

  for (int ww=0; ww<32; ww++){
    f32x4v N0,N1,N2;
    if (ww < 30){
      const size_t co_ = (size_t)(ww+2)*C2;
      N0 = hm ? *(const f32x4v*)(base + rm + co_) : z4;
      N1 =      *(const f32x4v*)(base + r0 + co_) ;
      N2 = hp ? *(const f32x4v*)(base + rp + co_) : z4;
    } else { N0=z4; N1=z4; N2=z4; }

    f32x4v s = bvv;
    s += wk[0]*A0 + wk[1]*B0 + wk[2]*C0;
    s += wk[3]*A1 + wk[4]*B1 + wk[5]*C1;
    s += wk[6]*A2 + wk[7]*B2 + wk[8]*C2c;

    u16x4 hv, lv;
    #pragma unroll
    for (int q=0;q<4;q++){
      float rlt = 0.5f*s[q]*(1.f + erff(s[q]*0.70710678118654752f));
      unsigned short hhv = f2bf(rlt);
      hv[q] = hhv; lv[q] = f2bf(rlt - bf2f(hhv));
    }
    *(u16x4*)(gh + obase + (size_t)ww*C2) = hv;
    *(u16x4*)(gl + obase + (size_t)ww*C2) = lv;

    A0=B0; A1=B1; A2=B2;
    B0=C0; B1=C1; B2=C2c;
    C0=N0; C1=N1; C2c=N2;
  }
}

// ---------------- launch ----------------
extern "C" void kernel_launch(void* const* d_in, const int* in_sizes, int n_in,
                              void* d_out, int out_size, void* d_ws, size_t ws_size,
                              hipStream_t stream) {
  const float* x1     = (const float*)d_in[0];
  const float* x2     = (const float*)d_in[1];
  const float* ln1_g  = (const float*)d_in[2];
  const float* ln1_b  = (const float*)d_in[3];
  const float* qkv_w  = (const float*)d_in[4];
  const float* ca_temp= (const float*)d_in[5];
  const float* proj_w = (const float*)d_in[6];
  const float* proj_b = (const float*)d_in[7];
  const float* ln3_g  = (const float*)d_in[8];
  const float* ln3_b  = (const float*)d_in[9];
  const float* rp_w   = (const float*)d_in[10];
  const float* rp_b   = (const float*)d_in[11];
  const float* cn_g   = (const float*)d_in[12];
  const float* cn_b   = (const float*)d_in[13];
  const float* ln2_g  = (const float*)d_in[14];
  const float* ln2_b  = (const float*)d_in[15];
  const float* fc1_w  = (const float*)d_in[16];
  const float* fc1_b  = (const float*)d_in[17];
  const float* dw_w   = (const float*)d_in[18];
  const float* dw_b   = (const float*)d_in[19];
  const float* fc2_w  = (const float*)d_in[20];
  const float* fc2_b  = (const float*)d_in[21];
  float* out = (float*)d_out;
  float* W   = (float*)d_ws;

  // ---- workspace layout (peak 50,331,648 floats = 192 MiB) ----
  // Phase A:
  unsigned short* ycoh = (unsigned short*)W;
  unsigned short* ycol = ycoh + (size_t)SZ_ND;
  unsigned short* coh  = ycoh;
  unsigned short* col  = ycol;
  float* qkvb = W + (size_t)SZ_ND;
  float* ch1  = W + 25165824ull;                         // LIVE until ln_concat
  float* ch2  = W + 31457280ull;                         // LIVE until ln_concat
  unsigned short* qkvwT_h  = (unsigned short*)(W + 37748736ull);
  unsigned short* qkvwT_l  = qkvwT_h + 442368u;
  unsigned short* projwT_h = qkvwT_l + 442368u;
  unsigned short* projwT_l = projwT_h + 147456u;
  // Phase B (cross-attn):
  float* n1  = W;                                        // [0, 6291456)
  float* n2  = W + (size_t)SZ_ND;                        // [6291456, 12582912)
  float* KS  = W + 2ull*SZ_ND;                           // [12582912, 18874368)
  unsigned short* QSh = (unsigned short*)(W + 3ull*SZ_ND); // [18874368, 25165824)
  unsigned short* QSl = QSh + (size_t)SZ_ND;
  unsigned short* rpw_h = (unsigned short*)(W + 37748736ull);  // over dead qkv/proj wts
  unsigned short* rpw_l = rpw_h + 294912u;
  unsigned short* n1t_h = (unsigned short*)(W + 38043648ull);  // [38043648, 44335104)
  unsigned short* n1t_l = n1t_h + (size_t)SZ_ND;
  unsigned short* KSt_h = (unsigned short*)(W + (size_t)SZ_ND); // over dead n2
  unsigned short* KSt_l = KSt_h + (size_t)SZ_ND;
  unsigned short* ctxT_h = (unsigned short*)W;                  // over dead n1 (2.36M fl)
  unsigned short* ctxT_l = ctxT_h + 2359296u;
  unsigned short* ATbh = (unsigned short*)(W + 2ull*SZ_ND);     // over dead KS
  unsigned short* ATbl = ATbh + (size_t)SZ_ND;
  float* rep = W;                                        // [0, 12582912) over dead ctxT/n1t-src
  // Phase C:
  float* txp  = out;
  float* h1   = W;
  unsigned short* y2h = (unsigned short*)(W + 25165824ull);
  unsigned short* y2l = y2h + (size_t)SZ_N2D;
  unsigned short* fc1wT_h = (unsigned short*)(W + 37748736ull);
  unsigned short* fc1wT_l = fc1wT_h + 1179648u;
  unsigned short* gh = (unsigned short*)(W + 25165824ull);
  unsigned short* gl = gh + (size_t)SZ_NC2;
  unsigned short* fc2wT_h = (unsigned short*)W;
  unsigned short* fc2wT_l = fc2wT_h + 1179648u;

  const int M = BN*NN;

  // ---- phase-A weight prep ----
  wconv_t_kernel<<<dim3(1152/32, DD/32), dim3(256), 0, stream>>>(qkv_w, qkvwT_h, qkvwT_l, DD, 1152);
  wconv_t_kernel<<<dim3(DD/32, DD/32), dim3(256), 0, stream>>>(proj_w, projwT_h, projwT_l, DD, DD);

  // ---- channel attention, stream 1 ----
  ln_split_kernel<<<dim3(M), dim3(256), 0, stream>>>(x1, ln1_g, ln1_b, ycoh, ycol, DD);
  gemm_bf16x3s_kernel<false,false,false><<<dim3(1152/128, M/128), dim3(256), 0, stream>>>(
      ycoh, ycol, qkvwT_h, qkvwT_l, nullptr, nullptr, qkvb, nullptr, nullptr, M, 1152, DD, 0,0,0);
  chattn_mfma_kernel<<<dim3(BN*NHEAD), dim3(256), 0, stream>>>(qkvb, ca_temp, coh, col);
  gemm_bf16x3s_kernel<true,true,false><<<dim3(DD/128, M/128), dim3(256), 0, stream>>>(
      coh, col, projwT_h, projwT_l, proj_b, x1, ch1, nullptr, nullptr, M, DD, DD, 0,0,0);

  // ---- channel attention, stream 2 ----
  ln_split_kernel<<<dim3(M), dim3(256), 0, stream>>>(x2, ln1_g, ln1_b, ycoh, ycol, DD);
  gemm_bf16x3s_kernel<false,false,false><<<dim3(1152/128, M/128), dim3(256), 0, stream>>>(
      ycoh, ycol, qkvwT_h, qkvwT_l, nullptr, nullptr, qkvb, nullptr, nullptr, M, 1152, DD, 0,0,0);
  chattn_mfma_kernel<<<dim3(BN*NHEAD), dim3(256), 0, stream>>>(qkvb, ca_temp, coh, col);
  gemm_bf16x3s_kernel<true,true,false><<<dim3(DD/128, M/128), dim3(256), 0, stream>>>(
      coh, col, projwT_h, projwT_l, proj_b, x2, ch2, nullptr, nullptr, M, DD, DD, 0,0,0);

  // ---- cross attention ----
  wconv_kernel<<<dim3(294912/256), dim3(256), 0, stream>>>(rp_w, rpw_h, rpw_l, 294912);
  ln_kernel<<<dim3(M), dim3(256), 0, stream>>>(ch1, ln3_g, ln3_b, n1, DD);
  ln_kernel<<<dim3(M), dim3(256), 0, stream>>>(ch2, ln3_g, ln3_b, n2, DD);
  rowsoftmax_split_kernel<<<dim3(M), dim3(256), 0, stream>>>(n2, QSh, QSl, DD);
  colsoftmax_kernel<<<dim3(DD/64, BN), dim3(256), 0, stream>>>(n2, KS);
  // n1t[b][d][n] = n1[b][n][d] ; KSt[b][d][n] = KS[b][n][d]   (batched transpose+split)
  tsplit_kernel<<<dim3(DD/32, NN/32, BN), dim3(256), 0, stream>>>(n1, n1t_h, n1t_l, NN, DD);
  tsplit_kernel<<<dim3(DD/32, NN/32, BN), dim3(256), 0, stream>>>(KS, KSt_h, KSt_l, NN, DD);
  // ctxT[b][d][e] = sum_n n1[n][d]*KS[n][e]  (= ctx[e][d]; B-layout for ATb GEMM)
  gemm_bf16x3s_kernel<false,false,true><<<dim3(DD/128, DD/128, BN), dim3(256), 0, stream>>>(
      n1t_h, n1t_l, KSt_h, KSt_l, nullptr, nullptr, nullptr, ctxT_h, ctxT_l,
      DD, DD, NN, (size_t)DD*NN, (size_t)DD*NN, (size_t)DD*DD);
  // ATb[b][n][d] = sum_e QS[n][e]*ctxT[d][e]  (split out, feeds rep GEMM as A)
  gemm_bf16x3s_kernel<false,false,true><<<dim3(DD/128, NN/128, BN), dim3(256), 0, stream>>>(
      QSh, QSl, ctxT_h, ctxT_l, nullptr, nullptr, nullptr, ATbh, ATbl,
      NN, DD, DD, (size_t)NN*DD, (size_t)DD*DD, (size_t)NN*DD);
  // rep = ATb [M,D] * rp_w^T + rp_b -> [M,768]
  gemm_bf16x3s_kernel<true,false,false><<<dim3(D2/128, M/128), dim3(256), 0, stream>>>(
      ATbh, ATbl, rpw_h, rpw_l, rp_b, nullptr, rep, nullptr, nullptr, M, D2, DD, 0,0,0);
  // tx = concat(ch1,ch2) + LN(rep)
  ln_concat_kernel<<<dim3(M), dim3(256), 0, stream>>>(rep, cn_g, cn_b, ch1, ch2, txp);

  // ---- mix FFN ----
  wconv_t_kernel<<<dim3(C2/32, D2/32), dim3(256), 0, stream>>>(fc1_w, fc1wT_h, fc1wT_l, D2, C2);
  ln_split_kernel<<<dim3(M), dim3(256), 0, stream>>>(txp, ln2_g, ln2_b, y2h, y2l, D2);
  gemm_bf16x3s_kernel<true,false,false><<<dim3(C2/128, M/128), dim3(256), 0, stream>>>(
      y2h, y2l, fc1wT_h, fc1wT_l, fc1_b, nullptr, h1, nullptr, nullptr, M, C2, D2, 0,0,0);
  dwconv_gelu_kernel<<<dim3(196608/256), dim3(256), 0, stream>>>(h1, dw_w, dw_b, gh, gl);
  wconv_t_kernel<<<dim3(D2/32, C2/32), dim3(256), 0, stream>>>(fc2_w, fc2wT_h, fc2wT_l, C2, D2);
  gemm_bf16x3s_kernel<true,true,false><<<dim3(D2/128, M/128), dim3(256), 0, stream>>>(
      gh, gl, fc2wT_h, fc2wT_l, fc2_b, txp, out, nullptr, nullptr, M, D2, C2, 0,0,0);
}